// Round 2
// baseline (1422.149 us; speedup 1.0000x reference)
//
#include <hip/hip_runtime.h>
#include <cfloat>
#include <cstdint>

#define NB 32
#define NP 1024
#define NK 20
#define NPTS 32768  // NB*NP

// ---------------------------------------------------------------------------
// d2[p] = sum_d x[p,d]^2. FMA order matches kknn's dot so self-dist is exact 0.
// ---------------------------------------------------------------------------
__global__ __launch_bounds__(256) void kd2(const float* __restrict__ x, int dim,
                                           float* __restrict__ d2) {
  int p = blockIdx.x * 256 + threadIdx.x;
  if (p >= NPTS) return;
  if (dim == 64) {
    const float4* xr = (const float4*)(x + (size_t)p * 64);
    float a0 = 0.f, a1 = 0.f, a2 = 0.f, a3 = 0.f;
#pragma unroll
    for (int dq = 0; dq < 16; dq++) {
      float4 v = xr[dq];
      a0 = fmaf(v.x, v.x, a0);
      a1 = fmaf(v.y, v.y, a1);
      a2 = fmaf(v.z, v.z, a2);
      a3 = fmaf(v.w, v.w, a3);
    }
    d2[p] = (a0 + a1) + (a2 + a3);
  } else {
    float s = 0.f;
#pragma unroll
    for (int d = 0; d < 3; d++) {
      float v = x[p * 3 + d];
      s = fmaf(v, v, s);
    }
    d2[p] = s;
  }
}

// ---------------------------------------------------------------------------
// kNN with in-kernel merge. Block = 256 thr = 64 points x 4 q-quarters.
// Thread (pt,qt) scans q = qt (mod 4) within each 64-q tile (256 q total),
// keeps top-20 (replace-worst). Then two-stage rank-merge in LDS -> idx.
// Tie-break: smaller index (lax.top_k stability). Order irrelevant downstream
// (max-aggregation), only the SET matters, but ranks give it anyway.
// ---------------------------------------------------------------------------
template <int DIM>
__global__ __launch_bounds__(256) void kknn(const float* __restrict__ x,
                                            const float* __restrict__ d2,
                                            int* __restrict__ idxo) {
  constexpr int STR = (DIM == 64) ? 68 : 4;
  __shared__ float smem[10240];  // 40 KB: tile area / merge area (reused)
  float* tile = smem;            // [64][STR]
  float* dt = smem + 64 * STR;   // [64]
  float* mD = smem;              // [64][80]
  int* mI = (int*)(smem + 5120); // [64][80]

  const int tid = threadIdx.x;
  const int pt = tid & 63;
  const int qt = tid >> 6;  // quarter = wave id
  const int cloud = blockIdx.x >> 4;
  const int blk = blockIdx.x & 15;
  const int p = cloud * 1024 + blk * 64 + pt;
  const int cbase = cloud * 1024;

  float xp[DIM];
  if constexpr (DIM == 64) {
    const float4* xr = (const float4*)(x + (size_t)p * 64);
#pragma unroll
    for (int dq = 0; dq < 16; dq++) {
      float4 t4 = xr[dq];
      xp[dq * 4 + 0] = t4.x;
      xp[dq * 4 + 1] = t4.y;
      xp[dq * 4 + 2] = t4.z;
      xp[dq * 4 + 3] = t4.w;
    }
  } else {
#pragma unroll
    for (int d = 0; d < DIM; d++) xp[d] = x[p * DIM + d];
  }
  const float d2p = d2[p];

  float bd[NK];
  int bi[NK];
#pragma unroll
  for (int s = 0; s < NK; s++) {
    bd[s] = FLT_MAX;
    bi[s] = 0x7fffffff;
  }
  float wd = FLT_MAX;
  int wi = 0x7fffffff;
  int wsl = 0;

  for (int t = 0; t < 16; t++) {
    __syncthreads();  // protect tile from previous iteration's readers
    if constexpr (DIM == 64) {
      const int r = tid >> 2, ch = tid & 3;
      const float4* src = (const float4*)(x + (size_t)(cbase + t * 64 + r) * 64 + ch * 16);
      float4* dst = (float4*)&tile[r * STR + ch * 16];
#pragma unroll
      for (int i = 0; i < 4; i++) dst[i] = src[i];
      if (tid < 64) dt[tid] = d2[cbase + t * 64 + tid];
    } else {
      if (tid < 64) {
#pragma unroll
        for (int d = 0; d < 3; d++) tile[tid * STR + d] = x[(cbase + t * 64 + tid) * 3 + d];
        dt[tid] = d2[cbase + t * 64 + tid];
      }
    }
    __syncthreads();

    for (int jj = 0; jj < 16; jj++) {
      const int j = jj * 4 + qt;  // wave-uniform -> broadcast LDS reads
      float dot;
      if constexpr (DIM == 64) {
        const float4* tq = (const float4*)&tile[j * STR];
        float a0 = 0.f, a1 = 0.f, a2 = 0.f, a3 = 0.f;
#pragma unroll
        for (int dq = 0; dq < 16; dq++) {
          float4 q4 = tq[dq];
          a0 = fmaf(xp[dq * 4 + 0], q4.x, a0);
          a1 = fmaf(xp[dq * 4 + 1], q4.y, a1);
          a2 = fmaf(xp[dq * 4 + 2], q4.z, a2);
          a3 = fmaf(xp[dq * 4 + 3], q4.w, a3);
        }
        dot = (a0 + a1) + (a2 + a3);
      } else {
        float s = 0.f;
#pragma unroll
        for (int d = 0; d < DIM; d++) s = fmaf(xp[d], tile[j * STR + d], s);
        dot = s;
      }
      const float dist = fmaf(-2.f, dot, d2p + dt[j]);
      const int qg = cbase + t * 64 + j;
      const bool ins = (dist < wd) || (dist == wd && qg < wi);
      if (ins) {
#pragma unroll
        for (int s = 0; s < NK; s++)
          if (s == wsl) {
            bd[s] = dist;
            bi[s] = qg;
          }
        wd = bd[0];
        wi = bi[0];
        wsl = 0;
#pragma unroll
        for (int s = 1; s < NK; s++) {
          const bool worse = (bd[s] > wd) || (bd[s] == wd && bi[s] > wi);
          if (worse) {
            wd = bd[s];
            wi = bi[s];
            wsl = s;
          }
        }
      }
    }
  }
  __syncthreads();  // tile dead; switch to merge layout
#pragma unroll
  for (int s = 0; s < NK; s++) {
    mD[pt * 80 + qt * 20 + s] = bd[s];
    mI[pt * 80 + qt * 20 + s] = bi[s];
  }
  __syncthreads();

  // stage A: 128 threads each merge a pair of 20-lists (40 -> 20), in place
  if (tid < 128) {
    const int pt2 = tid >> 1, h = tid & 1;
    const int base = pt2 * 80 + h * 40;
    float cd[40];
    int ci[40];
#pragma unroll
    for (int a = 0; a < 40; a++) {
      cd[a] = mD[base + a];
      ci[a] = mI[base + a];
    }
    int rank[40];
#pragma unroll
    for (int a = 0; a < 40; a++) rank[a] = 0;
#pragma unroll
    for (int a = 0; a < 40; a++)
#pragma unroll
      for (int b = a + 1; b < 40; b++) {
        const bool abet = (cd[a] < cd[b]) || (cd[a] == cd[b] && ci[a] < ci[b]);
        if (abet)
          rank[b]++;
        else
          rank[a]++;
      }
#pragma unroll
    for (int a = 0; a < 40; a++)
      if (rank[a] < NK) {
        mD[base + rank[a]] = cd[a];
        mI[base + rank[a]] = ci[a];
      }
  }
  __syncthreads();

  // stage B: 64 threads merge the two stage-A winners -> final 20 -> global
  if (tid < 64) {
    const int base = tid * 80;
    float cd[40];
    int ci[40];
#pragma unroll
    for (int a = 0; a < 20; a++) {
      cd[a] = mD[base + a];
      ci[a] = mI[base + a];
      cd[20 + a] = mD[base + 40 + a];
      ci[20 + a] = mI[base + 40 + a];
    }
    int rank[40];
#pragma unroll
    for (int a = 0; a < 40; a++) rank[a] = 0;
#pragma unroll
    for (int a = 0; a < 40; a++)
#pragma unroll
      for (int b = a + 1; b < 40; b++) {
        const bool abet = (cd[a] < cd[b]) || (cd[a] == cd[b] && ci[a] < ci[b]);
        if (abet)
          rank[b]++;
        else
          rank[a]++;
      }
    const int po = cloud * 1024 + blk * 64 + tid;
#pragma unroll
    for (int a = 0; a < 40; a++)
      if (rank[a] < NK) idxo[po * NK + rank[a]] = ci[a];
  }
}

// ---------------------------------------------------------------------------
// zero the 42 stat accumulators (replaces hipMemsetAsync for capture safety)
// ---------------------------------------------------------------------------
__global__ void kzero(double* __restrict__ S) {
  if (threadIdx.x < 42) S[threadIdx.x] = 0.0;
}

// ---------------------------------------------------------------------------
// Edge-feature moments: S[0:6]=sum e, S[6:42]=sum e e^T  (e=[xi, xj-xi])
// ---------------------------------------------------------------------------
__global__ __launch_bounds__(256) void kstats(const float* __restrict__ pos,
                                              const int* __restrict__ idx,
                                              double* __restrict__ S) {
  int p = blockIdx.x * 256 + threadIdx.x;
  float xi0 = pos[p * 3], xi1 = pos[p * 3 + 1], xi2 = pos[p * 3 + 2];
  float s1[6];
  float s2[36];
#pragma unroll
  for (int a = 0; a < 6; a++) s1[a] = 0.f;
#pragma unroll
  for (int a = 0; a < 36; a++) s2[a] = 0.f;
  for (int k = 0; k < NK; k++) {
    int j = idx[p * NK + k];
    float e[6];
    e[0] = xi0;
    e[1] = xi1;
    e[2] = xi2;
    e[3] = pos[j * 3] - xi0;
    e[4] = pos[j * 3 + 1] - xi1;
    e[5] = pos[j * 3 + 2] - xi2;
#pragma unroll
    for (int a = 0; a < 6; a++) {
      s1[a] += e[a];
#pragma unroll
      for (int b = 0; b < 6; b++) s2[a * 6 + b] = fmaf(e[a], e[b], s2[a * 6 + b]);
    }
  }
  bool lead = (threadIdx.x & 63) == 0;
#pragma unroll
  for (int a = 0; a < 6; a++) {
    float v = s1[a];
#pragma unroll
    for (int m = 1; m < 64; m <<= 1) v += __shfl_xor(v, m, 64);
    if (lead) atomicAdd(&S[a], (double)v);
  }
#pragma unroll
  for (int a = 0; a < 36; a++) {
    float v = s2[a];
#pragma unroll
    for (int m = 1; m < 64; m <<= 1) v += __shfl_xor(v, m, 64);
    if (lead) atomicAdd(&S[6 + a], (double)v);
  }
}

// BN scale/shift from moments (exact in double)
__global__ void kbn(const double* __restrict__ S, const float* __restrict__ W1a,
                    const float* __restrict__ b1a, const float* __restrict__ g1,
                    const float* __restrict__ be1, float* __restrict__ ss) {
  int c = threadIdx.x;  // 64
  double w[6];
#pragma unroll
  for (int d = 0; d < 6; d++) w[d] = (double)W1a[d * 64 + c];
  double b = (double)b1a[c];
  const double invN = 1.0 / (double)((size_t)NPTS * NK);
  double m1 = 0.0;
#pragma unroll
  for (int d = 0; d < 6; d++) m1 += w[d] * S[d];
  m1 *= invN;
  double q = 0.0;
#pragma unroll
  for (int a = 0; a < 6; a++)
#pragma unroll
    for (int d = 0; d < 6; d++) q += w[a] * w[d] * S[6 + a * 6 + d];
  q *= invN;
  double mu = m1 + b;
  double eh2 = q + 2.0 * b * m1 + b * b;
  double var = eh2 - mu * mu;
  if (var < 0.0) var = 0.0;
  double inv = 1.0 / sqrt(var + 1e-5);
  double sc = (double)g1[c] * inv;
  ss[c] = (float)sc;
  ss[64 + c] = (float)((double)be1[c] - mu * sc);
}

// ---------------------------------------------------------------------------
// EdgeConv1 fused: per edge z = relu(BN(e@W1a+b1a)), y = z@W1b, max over k.
// Wave per 16 points, lane = channel. z broadcast via per-wave LDS row.
// ---------------------------------------------------------------------------
__global__ __launch_bounds__(256) void kec1(const float* __restrict__ pos,
                                            const int* __restrict__ idx,
                                            const float* __restrict__ ss,
                                            const float* __restrict__ W1a,
                                            const float* __restrict__ b1a,
                                            const float* __restrict__ W1b,
                                            const float* __restrict__ b1b,
                                            float* __restrict__ x1) {
  const int lane = threadIdx.x & 63;
  const int wv = threadIdx.x >> 6;
  float wcol[64];
#pragma unroll
  for (int d = 0; d < 64; d++) wcol[d] = W1b[d * 64 + lane];
  float wdf[3], wbt[3];
#pragma unroll
  for (int d = 0; d < 3; d++) {
    float top = W1a[d * 64 + lane];
    float bot = W1a[(3 + d) * 64 + lane];
    wdf[d] = top - bot;
    wbt[d] = bot;
  }
  const float b1 = b1a[lane];
  const float sc = ss[lane];
  const float sh = ss[64 + lane];
  const float bb = b1b[lane];
  __shared__ float zb[4][64];
  float* z = zb[wv];
  const int p0 = (blockIdx.x * 4 + wv) * 16;
  for (int i = 0; i < 16; i++) {
    const int p = p0 + i;
    const float xi0 = pos[p * 3], xi1 = pos[p * 3 + 1], xi2 = pos[p * 3 + 2];
    const float pu = fmaf(xi2, wdf[2], fmaf(xi1, wdf[1], fmaf(xi0, wdf[0], b1)));
    float acc = -FLT_MAX;
    for (int k = 0; k < NK; k++) {
      const int j = idx[p * NK + k];
      const float xj0 = pos[j * 3], xj1 = pos[j * 3 + 1], xj2 = pos[j * 3 + 2];
      const float pv = fmaf(xj2, wbt[2], fmaf(xj1, wbt[1], xj0 * wbt[0]));
      const float zc = fmaxf(fmaf(pu + pv, sc, sh), 0.f);
      z[lane] = zc;
      __builtin_amdgcn_wave_barrier();
      float a0 = 0.f, a1 = 0.f, a2 = 0.f, a3 = 0.f;
#pragma unroll
      for (int dq = 0; dq < 16; dq++) {
        float4 zq = *(const float4*)&z[dq * 4];
        a0 = fmaf(zq.x, wcol[dq * 4 + 0], a0);
        a1 = fmaf(zq.y, wcol[dq * 4 + 1], a1);
        a2 = fmaf(zq.z, wcol[dq * 4 + 2], a2);
        a3 = fmaf(zq.w, wcol[dq * 4 + 3], a3);
      }
      __builtin_amdgcn_wave_barrier();
      acc = fmaxf(acc, (a0 + a1) + (a2 + a3));
    }
    x1[(size_t)p * 64 + lane] = acc + bb;
  }
}

// ---------------------------------------------------------------------------
// v[j,c] = x1_j . W2[64+d][c]  (the only per-point matmul EdgeConv2 needs)
// ---------------------------------------------------------------------------
__global__ __launch_bounds__(256) void kv(const float* __restrict__ x1,
                                          const float* __restrict__ W2,
                                          float* __restrict__ v) {
  const int c = threadIdx.x & 127;
  const int sub = threadIdx.x >> 7;
  float wv[64];
#pragma unroll
  for (int d = 0; d < 64; d++) wv[d] = W2[(64 + d) * 128 + c];
  const int pbase = blockIdx.x * 64 + sub * 32;
  for (int i = 0; i < 32; i++) {
    const int p = pbase + i;
    const float4* xr = (const float4*)(x1 + (size_t)p * 64);
    float a0 = 0.f, a1 = 0.f;
#pragma unroll
    for (int dq = 0; dq < 16; dq++) {
      float4 xv = xr[dq];
      a0 = fmaf(xv.x, wv[dq * 4 + 0], a0);
      a1 = fmaf(xv.y, wv[dq * 4 + 1], a1);
      a0 = fmaf(xv.z, wv[dq * 4 + 2], a0);
      a1 = fmaf(xv.w, wv[dq * 4 + 3], a1);
    }
    v[(size_t)p * 128 + c] = a0 + a1;
  }
}

// ---------------------------------------------------------------------------
// Precompute stacked epilogue matrix Bc (192x128) and const bias cb (128):
//  Bc[0:64]  = Wl_top + (W2_top - W2_bot) @ Wl_bot
//  Bc[64:192]= Wl_bot ;  cb = b2 @ Wl_bot + bl
// ---------------------------------------------------------------------------
__global__ __launch_bounds__(256) void kprep(const float* __restrict__ W2,
                                             const float* __restrict__ Wl,
                                             const float* __restrict__ b2,
                                             const float* __restrict__ bl,
                                             float* __restrict__ Bc,
                                             float* __restrict__ cb) {
  const int t = blockIdx.x * 256 + threadIdx.x;  // 8192
  const int d = t >> 7, c = t & 127;
  float s = Wl[d * 128 + c];
  for (int e = 0; e < 128; e++)
    s = fmaf(W2[d * 128 + e] - W2[(64 + d) * 128 + e], Wl[(64 + e) * 128 + c], s);
  Bc[d * 128 + c] = s;
  Bc[(64 + 2 * d) * 128 + c] = Wl[(64 + 2 * d) * 128 + c];
  Bc[(64 + 2 * d + 1) * 128 + c] = Wl[(64 + 2 * d + 1) * 128 + c];
  if (d == 0) {
    float sb = bl[c];
    for (int e = 0; e < 128; e++) sb = fmaf(b2[e], Wl[(64 + e) * 128 + c], sb);
    cb[c] = sb;
  }
}

// ---------------------------------------------------------------------------
// Final fused kernel: per 64-point tile build AT = [x1^T ; maxgather(v)^T]
// (192 x 64, k-major), GEMM with Bc (192x128), fused per-tile max epilogue.
// ---------------------------------------------------------------------------
#define ATS 72
#define BSS 132
__global__ __launch_bounds__(256) void kgemm(const float* __restrict__ x1,
                                             const float* __restrict__ v,
                                             const int* __restrict__ idx,
                                             const float* __restrict__ Bc,
                                             float* __restrict__ partial) {
  __shared__ float AT[192 * ATS];  // 55296 B
  __shared__ float BS[16 * BSS];   // 8448 B; idxs unioned here
  int* idxs = (int*)BS;            // [64*20] = 5120 B
  const int tid = threadIdx.x;
  const int cloud = blockIdx.x >> 4;
  const int mb = blockIdx.x & 15;
  const int pbase = cloud * 1024 + mb * 64;

#pragma unroll
  for (int r = 0; r < 5; r++) {
    int id = r * 256 + tid;  // 1280 idx entries
    idxs[id] = idx[(size_t)pbase * NK + id];
  }
#pragma unroll
  for (int r = 0; r < 16; r++) {
    int id = r * 256 + tid;
    int m = id >> 6, k = id & 63;
    AT[k * ATS + m] = x1[(size_t)(pbase + m) * 64 + k];
  }
  __syncthreads();
#pragma unroll
  for (int r = 0; r < 32; r++) {
    int id = r * 256 + tid;
    int m = id >> 7, kk = id & 127;
    const int* ip = &idxs[m * NK];
    float mx = -FLT_MAX;
#pragma unroll
    for (int k = 0; k < NK; k++) mx = fmaxf(mx, v[(size_t)ip[k] * 128 + kk]);
    AT[(64 + kk) * ATS + m] = mx;
  }
  __syncthreads();  // idxs dead; BS area reused for B tiles

  const int tr = tid >> 4, tc = tid & 15;
  float acc[4][8];
#pragma unroll
  for (int i = 0; i < 4; i++)
#pragma unroll
    for (int n = 0; n < 8; n++) acc[i][n] = 0.f;
  for (int kc = 0; kc < 12; kc++) {
#pragma unroll
    for (int r = 0; r < 8; r++) {
      int id = r * 256 + tid;
      int row = id >> 7, col = id & 127;
      BS[row * BSS + col] = Bc[(size_t)(kc * 16 + row) * 128 + col];
    }
    __syncthreads();
#pragma unroll
    for (int k = 0; k < 16; k++) {
      int kg = kc * 16 + k;
      float4 a = *(const float4*)&AT[kg * ATS + tr * 4];
      float4 b0 = *(const float4*)&BS[k * BSS + tc * 8];
      float4 b1 = *(const float4*)&BS[k * BSS + tc * 8 + 4];
      float av[4] = {a.x, a.y, a.z, a.w};
      float bv[8] = {b0.x, b0.y, b0.z, b0.w, b1.x, b1.y, b1.z, b1.w};
#pragma unroll
      for (int i = 0; i < 4; i++)
#pragma unroll
        for (int n = 0; n < 8; n++) acc[i][n] = fmaf(av[i], bv[n], acc[i][n]);
    }
    __syncthreads();
  }
#pragma unroll
  for (int n = 0; n < 8; n++) {
    float m4 = fmaxf(fmaxf(acc[0][n], acc[1][n]), fmaxf(acc[2][n], acc[3][n]));
    BS[tr * BSS + tc * 8 + n] = m4;
  }
  __syncthreads();
  if (tid < 128) {
    float m = -FLT_MAX;
#pragma unroll
    for (int rr = 0; rr < 16; rr++) m = fmaxf(m, BS[rr * BSS + tid]);
    partial[(size_t)blockIdx.x * 128 + tid] = m;
  }
}

// out[b,c] = max over 16 tile partials + cb[c]
__global__ __launch_bounds__(256) void kred(const float* __restrict__ partial,
                                            const float* __restrict__ cb,
                                            float* __restrict__ out) {
  int t = blockIdx.x * 256 + threadIdx.x;  // 4096
  int b = t >> 7, c = t & 127;
  float m = -FLT_MAX;
#pragma unroll
  for (int mb = 0; mb < 16; mb++) m = fmaxf(m, partial[(size_t)(b * 16 + mb) * 128 + c]);
  out[t] = m + cb[c];
}

// ---------------------------------------------------------------------------
extern "C" void kernel_launch(void* const* d_in, const int* in_sizes, int n_in,
                              void* d_out, int out_size, void* d_ws, size_t ws_size,
                              hipStream_t stream) {
  const float* pos = (const float*)d_in[0];
  const float* W1a = (const float*)d_in[1];
  const float* b1a = (const float*)d_in[2];
  const float* g1 = (const float*)d_in[3];
  const float* be1 = (const float*)d_in[4];
  const float* W1b = (const float*)d_in[5];
  const float* b1b = (const float*)d_in[6];
  const float* W2 = (const float*)d_in[7];
  const float* b2 = (const float*)d_in[8];
  const float* Wl = (const float*)d_in[9];
  const float* bl = (const float*)d_in[10];
  float* out = (float*)d_out;

  // Workspace layout (floats). Total 7,070,080 floats = 28.3 MB.
  float* ws = (float*)d_ws;
  float* x1 = ws;                        // 2,097,152
  float* v = ws + 2097152;               // 4,194,304
  int* idx = (int*)(ws + 6291456);       // 655,360
  float* d2b = ws + 6946816;             // 32,768
  double* S = (double*)(ws + 6979584);   // 42 doubles (84 slots)
  float* Bc = ws + 6979712;              // 24,576
  float* cb = ws + 7004288;              // 128
  float* ss = ws + 7004416;              // 128
  float* partial = ws + 7004544;         // 65,536  -> end 7,070,080

  if (ws_size < (size_t)7070080 * sizeof(float)) return;  // fail soft, not fault

  // layer 1: kNN on pos (3D)
  kd2<<<128, 256, 0, stream>>>(pos, 3, d2b);
  kknn<3><<<512, 256, 0, stream>>>(pos, d2b, idx);

  // EdgeConv1 (analytic BN via exact 6-dim moments)
  kzero<<<1, 64, 0, stream>>>(S);
  kstats<<<128, 256, 0, stream>>>(pos, idx, S);
  kbn<<<1, 64, 0, stream>>>(S, W1a, b1a, g1, be1, ss);
  kec1<<<512, 256, 0, stream>>>(pos, idx, ss, W1a, b1a, W1b, b1b, x1);

  // layer 2: kNN on x1 (64D)
  kd2<<<128, 256, 0, stream>>>(x1, 64, d2b);
  kknn<64><<<512, 256, 0, stream>>>(x1, d2b, idx);

  // EdgeConv2 factored + fused final linear + pool
  kv<<<512, 256, 0, stream>>>(x1, W2, v);
  kprep<<<32, 256, 0, stream>>>(W2, Wl, b2, bl, Bc, cb);
  kgemm<<<512, 256, 0, stream>>>(x1, v, idx, Bc, partial);
  kred<<<16, 256, 0, stream>>>(partial, cb, out);
}

// Round 3
// 889.561 us; speedup vs baseline: 1.5987x; 1.5987x over previous
//
#include <hip/hip_runtime.h>
#include <cfloat>
#include <cstdint>

#define NB 32
#define NP 1024
#define NK 20
#define NPTS 32768  // NB*NP

// ---------------------------------------------------------------------------
// d2[p] = sum x^2, SINGLE sequential FMA chain (order-matched with kdist's
// per-acc chain so diagonal dist = fmaf(-2,d2p,2*d2p) = exact 0).
// ---------------------------------------------------------------------------
__global__ __launch_bounds__(256) void kd2(const float* __restrict__ x, int dim,
                                           float* __restrict__ d2) {
  int p = blockIdx.x * 256 + threadIdx.x;
  if (p >= NPTS) return;
  if (dim == 64) {
    const float4* xr = (const float4*)(x + (size_t)p * 64);
    float s = 0.f;
#pragma unroll
    for (int dq = 0; dq < 16; dq++) {
      float4 v = xr[dq];
      s = fmaf(v.x, v.x, s);
      s = fmaf(v.y, v.y, s);
      s = fmaf(v.z, v.z, s);
      s = fmaf(v.w, v.w, s);
    }
    d2[p] = s;
  } else {
    float s = 0.f;
#pragma unroll
    for (int d = 0; d < 3; d++) {
      float v = x[p * 3 + d];
      s = fmaf(v, v, s);
    }
    d2[p] = s;
  }
}

// ---------------------------------------------------------------------------
// kdist: full per-cloud distance matrix, 128x128 tile per block.
// D[cloud_local*1024 + r][q] = d2[r]+d2[q]-2*dot(x_r,x_q), fp32.
// ---------------------------------------------------------------------------
template <int DIM>
__global__ __launch_bounds__(256) void kdist(const float* __restrict__ x,
                                             const float* __restrict__ d2,
                                             int c0, float* __restrict__ D) {
  constexpr int KC = (DIM == 64) ? 32 : 3;
  __shared__ float As[KC][132];
  __shared__ float Bs[KC][132];
  const int tid = threadIdx.x;
  const int cloud = blockIdx.x >> 6;  // within chunk
  const int t = blockIdx.x & 63;
  const int tr0 = (t >> 3) * 128, tc0 = (t & 7) * 128;
  const int cb = (c0 + cloud) * 1024;
  const int tr = tid >> 4, tc = tid & 15;

  float acc[8][8];
#pragma unroll
  for (int i = 0; i < 8; i++)
#pragma unroll
    for (int j = 0; j < 8; j++) acc[i][j] = 0.f;

  for (int kc = 0; kc < DIM; kc += KC) {
    __syncthreads();
    if constexpr (DIM == 64) {
      const int row = tid >> 1, seg = tid & 1;
      const float4* sa = (const float4*)(x + (size_t)(cb + tr0 + row) * 64 + kc + seg * 16);
      const float4* sb = (const float4*)(x + (size_t)(cb + tc0 + row) * 64 + kc + seg * 16);
#pragma unroll
      for (int i = 0; i < 4; i++) {
        float4 va = sa[i];
        float4 vb = sb[i];
        const int k0 = seg * 16 + i * 4;
        As[k0 + 0][row] = va.x;
        As[k0 + 1][row] = va.y;
        As[k0 + 2][row] = va.z;
        As[k0 + 3][row] = va.w;
        Bs[k0 + 0][row] = vb.x;
        Bs[k0 + 1][row] = vb.y;
        Bs[k0 + 2][row] = vb.z;
        Bs[k0 + 3][row] = vb.w;
      }
    } else {
      if (tid < 128) {
#pragma unroll
        for (int d = 0; d < 3; d++) {
          As[d][tid] = x[(size_t)(cb + tr0 + tid) * 3 + d];
          Bs[d][tid] = x[(size_t)(cb + tc0 + tid) * 3 + d];
        }
      }
    }
    __syncthreads();
#pragma unroll
    for (int k = 0; k < KC; k++) {
      float a[8], b[8];
      *(float4*)&a[0] = *(const float4*)&As[k][tr * 8];
      *(float4*)&a[4] = *(const float4*)&As[k][tr * 8 + 4];
      *(float4*)&b[0] = *(const float4*)&Bs[k][tc * 8];
      *(float4*)&b[4] = *(const float4*)&Bs[k][tc * 8 + 4];
#pragma unroll
      for (int i = 0; i < 8; i++)
#pragma unroll
        for (int j = 0; j < 8; j++) acc[i][j] = fmaf(a[i], b[j], acc[i][j]);
    }
  }
  float d2r[8], d2c[8];
#pragma unroll
  for (int i = 0; i < 8; i++) d2r[i] = d2[cb + tr0 + tr * 8 + i];
#pragma unroll
  for (int j = 0; j < 8; j++) d2c[j] = d2[cb + tc0 + tc * 8 + j];
#pragma unroll
  for (int i = 0; i < 8; i++) {
    float o[8];
#pragma unroll
    for (int j = 0; j < 8; j++) o[j] = fmaf(-2.f, acc[i][j], d2r[i] + d2c[j]);
    float* dst = &D[(size_t)(cloud * 1024 + tr0 + tr * 8 + i) * 1024 + tc0 + tc * 8];
    *(float4*)&dst[0] = *(const float4*)&o[0];
    *(float4*)&dst[4] = *(const float4*)&o[4];
  }
}

// ---------------------------------------------------------------------------
// kselect: exact top-20 per point from its 1024-dist row. Branch-free:
// sortable-uint key (handles tiny negative dists), packed (key<<10)|q gives
// unique keys + index tie-break. 64 lanes x 16 keys in VGPR; 20 rounds of
// per-lane min-above-last + wave butterfly min. No LDS, no divergence.
// ---------------------------------------------------------------------------
__global__ __launch_bounds__(256) void kselect(const float* __restrict__ D,
                                               int c0, int* __restrict__ idxo) {
  const int lane = threadIdx.x & 63;
  const int sub = threadIdx.x >> 6;
  const int pchunk = blockIdx.x * 4 + sub;      // point within chunk
  const int pg = c0 * 1024 + pchunk;            // global point
  const int gbase = (pg >> 10) << 10;           // cloud base (global)

  unsigned long long key[16];
  const float4* dr = (const float4*)(D + (size_t)pchunk * 1024 + lane * 4);
#pragma unroll
  for (int i = 0; i < 4; i++) {
    float4 d4 = dr[i * 64];  // q = i*256 + lane*4 ..+3
    float dv[4] = {d4.x, d4.y, d4.z, d4.w};
#pragma unroll
    for (int j = 0; j < 4; j++) {
      unsigned int u = __float_as_uint(dv[j]);
      u ^= (((int)u >> 31) | 0x80000000u);  // sortable transform
      key[i * 4 + j] = ((unsigned long long)u << 10) | (unsigned)(i * 256 + lane * 4 + j);
    }
  }

  unsigned long long last = 0ULL;
  for (int r = 0; r < NK; r++) {
    unsigned long long m = ~0ULL;
#pragma unroll
    for (int i = 0; i < 16; i++) {
      const bool c = (key[i] > last) && (key[i] < m);
      m = c ? key[i] : m;
    }
#pragma unroll
    for (int s = 1; s < 64; s <<= 1) {
      unsigned long long o = __shfl_xor(m, s, 64);
      m = (o < m) ? o : m;
    }
    if (lane == 0) idxo[(size_t)pg * NK + r] = gbase + (int)(m & 1023u);
    last = m;
  }
}

// ---------------------------------------------------------------------------
// FALLBACK kNN (round-2 kernel, dot chain order-matched to new kd2).
// Used only if ws_size can't fit even a 1-cloud distance matrix.
// ---------------------------------------------------------------------------
template <int DIM>
__global__ __launch_bounds__(256) void kknn(const float* __restrict__ x,
                                            const float* __restrict__ d2,
                                            int* __restrict__ idxo) {
  constexpr int STR = (DIM == 64) ? 68 : 4;
  __shared__ float smem[10240];
  float* tile = smem;
  float* dt = smem + 64 * STR;
  float* mD = smem;
  int* mI = (int*)(smem + 5120);

  const int tid = threadIdx.x;
  const int pt = tid & 63;
  const int qt = tid >> 6;
  const int cloud = blockIdx.x >> 4;
  const int blk = blockIdx.x & 15;
  const int p = cloud * 1024 + blk * 64 + pt;
  const int cbase = cloud * 1024;

  float xp[DIM];
#pragma unroll
  for (int d = 0; d < DIM; d++) xp[d] = x[(size_t)p * DIM + d];
  const float d2p = d2[p];

  float bd[NK];
  int bi[NK];
#pragma unroll
  for (int s = 0; s < NK; s++) {
    bd[s] = FLT_MAX;
    bi[s] = 0x7fffffff;
  }
  float wd = FLT_MAX;
  int wi = 0x7fffffff;
  int wsl = 0;

  for (int t = 0; t < 16; t++) {
    __syncthreads();
    if (tid < 64) {
#pragma unroll
      for (int d = 0; d < DIM; d++) tile[tid * STR + d] = x[(size_t)(cbase + t * 64 + tid) * DIM + d];
      dt[tid] = d2[cbase + t * 64 + tid];
    }
    __syncthreads();
    for (int jj = 0; jj < 16; jj++) {
      const int j = jj * 4 + qt;
      float s = 0.f;
#pragma unroll
      for (int d = 0; d < DIM; d++) s = fmaf(xp[d], tile[j * STR + d], s);
      const float dist = fmaf(-2.f, s, d2p + dt[j]);
      const int qg = cbase + t * 64 + j;
      const bool ins = (dist < wd) || (dist == wd && qg < wi);
      if (ins) {
#pragma unroll
        for (int sl = 0; sl < NK; sl++)
          if (sl == wsl) {
            bd[sl] = dist;
            bi[sl] = qg;
          }
        wd = bd[0];
        wi = bi[0];
        wsl = 0;
#pragma unroll
        for (int sl = 1; sl < NK; sl++) {
          const bool worse = (bd[sl] > wd) || (bd[sl] == wd && bi[sl] > wi);
          if (worse) {
            wd = bd[sl];
            wi = bi[sl];
            wsl = sl;
          }
        }
      }
    }
  }
  __syncthreads();
#pragma unroll
  for (int s = 0; s < NK; s++) {
    mD[pt * 80 + qt * 20 + s] = bd[s];
    mI[pt * 80 + qt * 20 + s] = bi[s];
  }
  __syncthreads();
  if (tid < 128) {
    const int pt2 = tid >> 1, h = tid & 1;
    const int base = pt2 * 80 + h * 40;
    float cd[40];
    int ci[40];
#pragma unroll
    for (int a = 0; a < 40; a++) {
      cd[a] = mD[base + a];
      ci[a] = mI[base + a];
    }
    int rank[40];
#pragma unroll
    for (int a = 0; a < 40; a++) rank[a] = 0;
#pragma unroll
    for (int a = 0; a < 40; a++)
#pragma unroll
      for (int b = a + 1; b < 40; b++) {
        const bool abet = (cd[a] < cd[b]) || (cd[a] == cd[b] && ci[a] < ci[b]);
        if (abet)
          rank[b]++;
        else
          rank[a]++;
      }
#pragma unroll
    for (int a = 0; a < 40; a++)
      if (rank[a] < NK) {
        mD[base + rank[a]] = cd[a];
        mI[base + rank[a]] = ci[a];
      }
  }
  __syncthreads();
  if (tid < 64) {
    const int base = tid * 80;
    float cd[40];
    int ci[40];
#pragma unroll
    for (int a = 0; a < 20; a++) {
      cd[a] = mD[base + a];
      ci[a] = mI[base + a];
      cd[20 + a] = mD[base + 40 + a];
      ci[20 + a] = mI[base + 40 + a];
    }
    int rank[40];
#pragma unroll
    for (int a = 0; a < 40; a++) rank[a] = 0;
#pragma unroll
    for (int a = 0; a < 40; a++)
#pragma unroll
      for (int b = a + 1; b < 40; b++) {
        const bool abet = (cd[a] < cd[b]) || (cd[a] == cd[b] && ci[a] < ci[b]);
        if (abet)
          rank[b]++;
        else
          rank[a]++;
      }
    const int po = cloud * 1024 + blk * 64 + tid;
#pragma unroll
    for (int a = 0; a < 40; a++)
      if (rank[a] < NK) idxo[(size_t)po * NK + rank[a]] = ci[a];
  }
}

// ---------------------------------------------------------------------------
__global__ void kzero(double* __restrict__ S) {
  if (threadIdx.x < 42) S[threadIdx.x] = 0.0;
}

// Edge-feature moments: S[0:6]=sum e, S[6:42]=sum e e^T  (e=[xi, xj-xi])
__global__ __launch_bounds__(256) void kstats(const float* __restrict__ pos,
                                              const int* __restrict__ idx,
                                              double* __restrict__ S) {
  int p = blockIdx.x * 256 + threadIdx.x;
  float xi0 = pos[p * 3], xi1 = pos[p * 3 + 1], xi2 = pos[p * 3 + 2];
  float s1[6];
  float s2[36];
#pragma unroll
  for (int a = 0; a < 6; a++) s1[a] = 0.f;
#pragma unroll
  for (int a = 0; a < 36; a++) s2[a] = 0.f;
  for (int k = 0; k < NK; k++) {
    int j = idx[p * NK + k];
    float e[6];
    e[0] = xi0;
    e[1] = xi1;
    e[2] = xi2;
    e[3] = pos[j * 3] - xi0;
    e[4] = pos[j * 3 + 1] - xi1;
    e[5] = pos[j * 3 + 2] - xi2;
#pragma unroll
    for (int a = 0; a < 6; a++) {
      s1[a] += e[a];
#pragma unroll
      for (int b = 0; b < 6; b++) s2[a * 6 + b] = fmaf(e[a], e[b], s2[a * 6 + b]);
    }
  }
  bool lead = (threadIdx.x & 63) == 0;
#pragma unroll
  for (int a = 0; a < 6; a++) {
    float v = s1[a];
#pragma unroll
    for (int m = 1; m < 64; m <<= 1) v += __shfl_xor(v, m, 64);
    if (lead) atomicAdd(&S[a], (double)v);
  }
#pragma unroll
  for (int a = 0; a < 36; a++) {
    float v = s2[a];
#pragma unroll
    for (int m = 1; m < 64; m <<= 1) v += __shfl_xor(v, m, 64);
    if (lead) atomicAdd(&S[6 + a], (double)v);
  }
}

// BN scale/shift from moments (exact in double)
__global__ void kbn(const double* __restrict__ S, const float* __restrict__ W1a,
                    const float* __restrict__ b1a, const float* __restrict__ g1,
                    const float* __restrict__ be1, float* __restrict__ ss) {
  int c = threadIdx.x;  // 64
  double w[6];
#pragma unroll
  for (int d = 0; d < 6; d++) w[d] = (double)W1a[d * 64 + c];
  double b = (double)b1a[c];
  const double invN = 1.0 / (double)((size_t)NPTS * NK);
  double m1 = 0.0;
#pragma unroll
  for (int d = 0; d < 6; d++) m1 += w[d] * S[d];
  m1 *= invN;
  double q = 0.0;
#pragma unroll
  for (int a = 0; a < 6; a++)
#pragma unroll
    for (int d = 0; d < 6; d++) q += w[a] * w[d] * S[6 + a * 6 + d];
  q *= invN;
  double mu = m1 + b;
  double eh2 = q + 2.0 * b * m1 + b * b;
  double var = eh2 - mu * mu;
  if (var < 0.0) var = 0.0;
  double inv = 1.0 / sqrt(var + 1e-5);
  double sc = (double)g1[c] * inv;
  ss[c] = (float)sc;
  ss[64 + c] = (float)((double)be1[c] - mu * sc);
}

// ---------------------------------------------------------------------------
// EdgeConv1 fused: per edge z = relu(BN(e@W1a+b1a)), y = z@W1b, max over k.
// ---------------------------------------------------------------------------
__global__ __launch_bounds__(256) void kec1(const float* __restrict__ pos,
                                            const int* __restrict__ idx,
                                            const float* __restrict__ ss,
                                            const float* __restrict__ W1a,
                                            const float* __restrict__ b1a,
                                            const float* __restrict__ W1b,
                                            const float* __restrict__ b1b,
                                            float* __restrict__ x1) {
  const int lane = threadIdx.x & 63;
  const int wv = threadIdx.x >> 6;
  float wcol[64];
#pragma unroll
  for (int d = 0; d < 64; d++) wcol[d] = W1b[d * 64 + lane];
  float wdf[3], wbt[3];
#pragma unroll
  for (int d = 0; d < 3; d++) {
    float top = W1a[d * 64 + lane];
    float bot = W1a[(3 + d) * 64 + lane];
    wdf[d] = top - bot;
    wbt[d] = bot;
  }
  const float b1 = b1a[lane];
  const float sc = ss[lane];
  const float sh = ss[64 + lane];
  const float bb = b1b[lane];
  __shared__ float zb[4][64];
  float* z = zb[wv];
  const int p0 = (blockIdx.x * 4 + wv) * 16;
  for (int i = 0; i < 16; i++) {
    const int p = p0 + i;
    const float xi0 = pos[p * 3], xi1 = pos[p * 3 + 1], xi2 = pos[p * 3 + 2];
    const float pu = fmaf(xi2, wdf[2], fmaf(xi1, wdf[1], fmaf(xi0, wdf[0], b1)));
    float acc = -FLT_MAX;
    for (int k = 0; k < NK; k++) {
      const int j = idx[p * NK + k];
      const float xj0 = pos[j * 3], xj1 = pos[j * 3 + 1], xj2 = pos[j * 3 + 2];
      const float pv = fmaf(xj2, wbt[2], fmaf(xj1, wbt[1], xj0 * wbt[0]));
      const float zc = fmaxf(fmaf(pu + pv, sc, sh), 0.f);
      z[lane] = zc;
      __builtin_amdgcn_wave_barrier();
      float a0 = 0.f, a1 = 0.f, a2 = 0.f, a3 = 0.f;
#pragma unroll
      for (int dq = 0; dq < 16; dq++) {
        float4 zq = *(const float4*)&z[dq * 4];
        a0 = fmaf(zq.x, wcol[dq * 4 + 0], a0);
        a1 = fmaf(zq.y, wcol[dq * 4 + 1], a1);
        a2 = fmaf(zq.z, wcol[dq * 4 + 2], a2);
        a3 = fmaf(zq.w, wcol[dq * 4 + 3], a3);
      }
      __builtin_amdgcn_wave_barrier();
      acc = fmaxf(acc, (a0 + a1) + (a2 + a3));
    }
    x1[(size_t)p * 64 + lane] = acc + bb;
  }
}

// v[j,c] = x1_j . W2[64+d][c]
__global__ __launch_bounds__(256) void kv(const float* __restrict__ x1,
                                          const float* __restrict__ W2,
                                          float* __restrict__ v) {
  const int c = threadIdx.x & 127;
  const int sub = threadIdx.x >> 7;
  float wv[64];
#pragma unroll
  for (int d = 0; d < 64; d++) wv[d] = W2[(64 + d) * 128 + c];
  const int pbase = blockIdx.x * 64 + sub * 32;
  for (int i = 0; i < 32; i++) {
    const int p = pbase + i;
    const float4* xr = (const float4*)(x1 + (size_t)p * 64);
    float a0 = 0.f, a1 = 0.f;
#pragma unroll
    for (int dq = 0; dq < 16; dq++) {
      float4 xv = xr[dq];
      a0 = fmaf(xv.x, wv[dq * 4 + 0], a0);
      a1 = fmaf(xv.y, wv[dq * 4 + 1], a1);
      a0 = fmaf(xv.z, wv[dq * 4 + 2], a0);
      a1 = fmaf(xv.w, wv[dq * 4 + 3], a1);
    }
    v[(size_t)p * 128 + c] = a0 + a1;
  }
}

// Bc (192x128) and const bias cb (128)
__global__ __launch_bounds__(256) void kprep(const float* __restrict__ W2,
                                             const float* __restrict__ Wl,
                                             const float* __restrict__ b2,
                                             const float* __restrict__ bl,
                                             float* __restrict__ Bc,
                                             float* __restrict__ cb) {
  const int t = blockIdx.x * 256 + threadIdx.x;  // 8192
  const int d = t >> 7, c = t & 127;
  float s = Wl[d * 128 + c];
  for (int e = 0; e < 128; e++)
    s = fmaf(W2[d * 128 + e] - W2[(64 + d) * 128 + e], Wl[(64 + e) * 128 + c], s);
  Bc[d * 128 + c] = s;
  Bc[(64 + 2 * d) * 128 + c] = Wl[(64 + 2 * d) * 128 + c];
  Bc[(64 + 2 * d + 1) * 128 + c] = Wl[(64 + 2 * d + 1) * 128 + c];
  if (d == 0) {
    float sb = bl[c];
    for (int e = 0; e < 128; e++) sb = fmaf(b2[e], Wl[(64 + e) * 128 + c], sb);
    cb[c] = sb;
  }
}

// Final fused: AT = [x1^T ; maxgather(v)^T], GEMM with Bc, per-tile max.
#define ATS 72
#define BSS 132
__global__ __launch_bounds__(256) void kgemm(const float* __restrict__ x1,
                                             const float* __restrict__ v,
                                             const int* __restrict__ idx,
                                             const float* __restrict__ Bc,
                                             float* __restrict__ partial) {
  __shared__ float AT[192 * ATS];
  __shared__ float BS[16 * BSS];
  int* idxs = (int*)BS;
  const int tid = threadIdx.x;
  const int cloud = blockIdx.x >> 4;
  const int mb = blockIdx.x & 15;
  const int pbase = cloud * 1024 + mb * 64;

#pragma unroll
  for (int r = 0; r < 5; r++) {
    int id = r * 256 + tid;
    idxs[id] = idx[(size_t)pbase * NK + id];
  }
#pragma unroll
  for (int r = 0; r < 16; r++) {
    int id = r * 256 + tid;
    int m = id >> 6, k = id & 63;
    AT[k * ATS + m] = x1[(size_t)(pbase + m) * 64 + k];
  }
  __syncthreads();
#pragma unroll
  for (int r = 0; r < 32; r++) {
    int id = r * 256 + tid;
    int m = id >> 7, kk = id & 127;
    const int* ip = &idxs[m * NK];
    float mx = -FLT_MAX;
#pragma unroll
    for (int k = 0; k < NK; k++) mx = fmaxf(mx, v[(size_t)ip[k] * 128 + kk]);
    AT[(64 + kk) * ATS + m] = mx;
  }
  __syncthreads();

  const int tr = tid >> 4, tc = tid & 15;
  float acc[4][8];
#pragma unroll
  for (int i = 0; i < 4; i++)
#pragma unroll
    for (int n = 0; n < 8; n++) acc[i][n] = 0.f;
  for (int kc = 0; kc < 12; kc++) {
#pragma unroll
    for (int r = 0; r < 8; r++) {
      int id = r * 256 + tid;
      int row = id >> 7, col = id & 127;
      BS[row * BSS + col] = Bc[(size_t)(kc * 16 + row) * 128 + col];
    }
    __syncthreads();
#pragma unroll
    for (int k = 0; k < 16; k++) {
      int kg = kc * 16 + k;
      float4 a = *(const float4*)&AT[kg * ATS + tr * 4];
      float4 b0 = *(const float4*)&BS[k * BSS + tc * 8];
      float4 b1 = *(const float4*)&BS[k * BSS + tc * 8 + 4];
      float av[4] = {a.x, a.y, a.z, a.w};
      float bv[8] = {b0.x, b0.y, b0.z, b0.w, b1.x, b1.y, b1.z, b1.w};
#pragma unroll
      for (int i = 0; i < 4; i++)
#pragma unroll
        for (int n = 0; n < 8; n++) acc[i][n] = fmaf(av[i], bv[n], acc[i][n]);
    }
    __syncthreads();
  }
#pragma unroll
  for (int n = 0; n < 8; n++) {
    float m4 = fmaxf(fmaxf(acc[0][n], acc[1][n]), fmaxf(acc[2][n], acc[3][n]));
    BS[tr * BSS + tc * 8 + n] = m4;
  }
  __syncthreads();
  if (tid < 128) {
    float m = -FLT_MAX;
#pragma unroll
    for (int rr = 0; rr < 16; rr++) m = fmaxf(m, BS[rr * BSS + tid]);
    partial[(size_t)blockIdx.x * 128 + tid] = m;
  }
}

__global__ __launch_bounds__(256) void kred(const float* __restrict__ partial,
                                            const float* __restrict__ cb,
                                            float* __restrict__ out) {
  int t = blockIdx.x * 256 + threadIdx.x;  // 4096
  int b = t >> 7, c = t & 127;
  float m = -FLT_MAX;
#pragma unroll
  for (int mb = 0; mb < 16; mb++) m = fmaxf(m, partial[(size_t)(b * 16 + mb) * 128 + c]);
  out[t] = m + cb[c];
}

// ---------------------------------------------------------------------------
extern "C" void kernel_launch(void* const* d_in, const int* in_sizes, int n_in,
                              void* d_out, int out_size, void* d_ws, size_t ws_size,
                              hipStream_t stream) {
  const float* pos = (const float*)d_in[0];
  const float* W1a = (const float*)d_in[1];
  const float* b1a = (const float*)d_in[2];
  const float* g1 = (const float*)d_in[3];
  const float* be1 = (const float*)d_in[4];
  const float* W1b = (const float*)d_in[5];
  const float* b1b = (const float*)d_in[6];
  const float* W2 = (const float*)d_in[7];
  const float* b2 = (const float*)d_in[8];
  const float* Wl = (const float*)d_in[9];
  const float* bl = (const float*)d_in[10];
  float* out = (float*)d_out;

  // Base workspace (floats): 7,070,080 = 28.3 MB. D-matrix chunk after it.
  float* ws = (float*)d_ws;
  float* x1 = ws;                       // 2,097,152
  float* v = ws + 2097152;              // 4,194,304
  int* idx = (int*)(ws + 6291456);      // 655,360
  float* d2b = ws + 6946816;            // 32,768
  double* S = (double*)(ws + 6979584);  // 42 doubles (84 slots)
  float* Bc = ws + 6979712;             // 24,576
  float* cb = ws + 7004288;             // 128
  float* ss = ws + 7004416;             // 128
  float* partial = ws + 7004544;        // 65,536 -> end 7,070,080
  const size_t base = 7070080;
  float* D = ws + base;

  if (ws_size < base * sizeof(float)) return;  // fail soft

  // cloud-chunk size for the distance matrix (4 MB per cloud)
  size_t avail = ws_size / sizeof(float) - base;
  int nc = 0;
  for (int c = 32; c >= 1; c >>= 1)
    if ((size_t)c * 1024 * 1024 <= avail) {
      nc = c;
      break;
    }

  // --- layer 1: kNN on pos (3D) ---
  kd2<<<128, 256, 0, stream>>>(pos, 3, d2b);
  if (nc > 0) {
    for (int c0 = 0; c0 < NB; c0 += nc) {
      kdist<3><<<nc * 64, 256, 0, stream>>>(pos, d2b, c0, D);
      kselect<<<nc * 256, 256, 0, stream>>>(D, c0, idx);
    }
  } else {
    kknn<3><<<512, 256, 0, stream>>>(pos, d2b, idx);
  }

  // --- EdgeConv1 (analytic BN via exact 6-dim moments) ---
  kzero<<<1, 64, 0, stream>>>(S);
  kstats<<<128, 256, 0, stream>>>(pos, idx, S);
  kbn<<<1, 64, 0, stream>>>(S, W1a, b1a, g1, be1, ss);
  kec1<<<512, 256, 0, stream>>>(pos, idx, ss, W1a, b1a, W1b, b1b, x1);

  // --- layer 2: kNN on x1 (64D) ---
  kd2<<<128, 256, 0, stream>>>(x1, 64, d2b);
  if (nc > 0) {
    for (int c0 = 0; c0 < NB; c0 += nc) {
      kdist<64><<<nc * 64, 256, 0, stream>>>(x1, d2b, c0, D);
      kselect<<<nc * 256, 256, 0, stream>>>(D, c0, idx);
    }
  } else {
    kknn<64><<<512, 256, 0, stream>>>(x1, d2b, idx);
  }

  // --- EdgeConv2 factored + fused final linear + pool ---
  kv<<<512, 256, 0, stream>>>(x1, W2, v);
  kprep<<<32, 256, 0, stream>>>(W2, Wl, b2, bl, Bc, cb);
  kgemm<<<512, 256, 0, stream>>>(x1, v, idx, Bc, partial);
  kred<<<16, 256, 0, stream>>>(partial, cb, out);
}

// Round 4
// 672.248 us; speedup vs baseline: 2.1155x; 1.3233x over previous
//
#include <hip/hip_runtime.h>
#include <cfloat>
#include <cstdint>

#define NB 32
#define NP 1024
#define NK 20
#define NPTS 32768  // NB*NP

// ---------------------------------------------------------------------------
// d2[p] = sum x^2, SINGLE sequential FMA chain (order-matched with kdist's
// per-acc chain so diagonal dist = fmaf(-2,d2p,2*d2p) = exact 0).
// ---------------------------------------------------------------------------
__global__ __launch_bounds__(256) void kd2(const float* __restrict__ x, int dim,
                                           float* __restrict__ d2) {
  int p = blockIdx.x * 256 + threadIdx.x;
  if (p >= NPTS) return;
  if (dim == 64) {
    const float4* xr = (const float4*)(x + (size_t)p * 64);
    float s = 0.f;
#pragma unroll
    for (int dq = 0; dq < 16; dq++) {
      float4 v = xr[dq];
      s = fmaf(v.x, v.x, s);
      s = fmaf(v.y, v.y, s);
      s = fmaf(v.z, v.z, s);
      s = fmaf(v.w, v.w, s);
    }
    d2[p] = s;
  } else {
    float s = 0.f;
#pragma unroll
    for (int d = 0; d < 3; d++) {
      float v = x[p * 3 + d];
      s = fmaf(v, v, s);
    }
    d2[p] = s;
  }
}

// ---------------------------------------------------------------------------
// kdist: full per-cloud distance matrix, 128x128 tile per block.
// ---------------------------------------------------------------------------
template <int DIM>
__global__ __launch_bounds__(256) void kdist(const float* __restrict__ x,
                                             const float* __restrict__ d2,
                                             int c0, float* __restrict__ D) {
  constexpr int KC = (DIM == 64) ? 32 : 3;
  __shared__ float As[KC][132];
  __shared__ float Bs[KC][132];
  const int tid = threadIdx.x;
  const int cloud = blockIdx.x >> 6;  // within chunk
  const int t = blockIdx.x & 63;
  const int tr0 = (t >> 3) * 128, tc0 = (t & 7) * 128;
  const int cb = (c0 + cloud) * 1024;
  const int tr = tid >> 4, tc = tid & 15;

  float acc[8][8];
#pragma unroll
  for (int i = 0; i < 8; i++)
#pragma unroll
    for (int j = 0; j < 8; j++) acc[i][j] = 0.f;

  for (int kc = 0; kc < DIM; kc += KC) {
    __syncthreads();
    if constexpr (DIM == 64) {
      const int row = tid >> 1, seg = tid & 1;
      const float4* sa = (const float4*)(x + (size_t)(cb + tr0 + row) * 64 + kc + seg * 16);
      const float4* sb = (const float4*)(x + (size_t)(cb + tc0 + row) * 64 + kc + seg * 16);
#pragma unroll
      for (int i = 0; i < 4; i++) {
        float4 va = sa[i];
        float4 vb = sb[i];
        const int k0 = seg * 16 + i * 4;
        As[k0 + 0][row] = va.x;
        As[k0 + 1][row] = va.y;
        As[k0 + 2][row] = va.z;
        As[k0 + 3][row] = va.w;
        Bs[k0 + 0][row] = vb.x;
        Bs[k0 + 1][row] = vb.y;
        Bs[k0 + 2][row] = vb.z;
        Bs[k0 + 3][row] = vb.w;
      }
    } else {
      if (tid < 128) {
#pragma unroll
        for (int d = 0; d < 3; d++) {
          As[d][tid] = x[(size_t)(cb + tr0 + tid) * 3 + d];
          Bs[d][tid] = x[(size_t)(cb + tc0 + tid) * 3 + d];
        }
      }
    }
    __syncthreads();
#pragma unroll
    for (int k = 0; k < KC; k++) {
      float a[8], b[8];
      *(float4*)&a[0] = *(const float4*)&As[k][tr * 8];
      *(float4*)&a[4] = *(const float4*)&As[k][tr * 8 + 4];
      *(float4*)&b[0] = *(const float4*)&Bs[k][tc * 8];
      *(float4*)&b[4] = *(const float4*)&Bs[k][tc * 8 + 4];
#pragma unroll
      for (int i = 0; i < 8; i++)
#pragma unroll
        for (int j = 0; j < 8; j++) acc[i][j] = fmaf(a[i], b[j], acc[i][j]);
    }
  }
  float d2r[8], d2c[8];
#pragma unroll
  for (int i = 0; i < 8; i++) d2r[i] = d2[cb + tr0 + tr * 8 + i];
#pragma unroll
  for (int j = 0; j < 8; j++) d2c[j] = d2[cb + tc0 + tc * 8 + j];
#pragma unroll
  for (int i = 0; i < 8; i++) {
    float o[8];
#pragma unroll
    for (int j = 0; j < 8; j++) o[j] = fmaf(-2.f, acc[i][j], d2r[i] + d2c[j]);
    float* dst = &D[(size_t)(cloud * 1024 + tr0 + tr * 8 + i) * 1024 + tc0 + tc * 8];
    *(float4*)&dst[0] = *(const float4*)&o[0];
    *(float4*)&dst[4] = *(const float4*)&o[4];
  }
}

// ---------------------------------------------------------------------------
// kselect: exact top-20 per point from its 1024-dist row (branch-free).
// ---------------------------------------------------------------------------
__global__ __launch_bounds__(256) void kselect(const float* __restrict__ D,
                                               int c0, int* __restrict__ idxo) {
  const int lane = threadIdx.x & 63;
  const int sub = threadIdx.x >> 6;
  const int pchunk = blockIdx.x * 4 + sub;  // point within chunk
  const int pg = c0 * 1024 + pchunk;        // global point
  const int gbase = (pg >> 10) << 10;       // cloud base (global)

  unsigned long long key[16];
  const float4* dr = (const float4*)(D + (size_t)pchunk * 1024 + lane * 4);
#pragma unroll
  for (int i = 0; i < 4; i++) {
    float4 d4 = dr[i * 64];  // q = i*256 + lane*4 ..+3
    float dv[4] = {d4.x, d4.y, d4.z, d4.w};
#pragma unroll
    for (int j = 0; j < 4; j++) {
      unsigned int u = __float_as_uint(dv[j]);
      u ^= (((int)u >> 31) | 0x80000000u);  // sortable transform
      key[i * 4 + j] = ((unsigned long long)u << 10) | (unsigned)(i * 256 + lane * 4 + j);
    }
  }

  unsigned long long last = 0ULL;
  for (int r = 0; r < NK; r++) {
    unsigned long long m = ~0ULL;
#pragma unroll
    for (int i = 0; i < 16; i++) {
      const bool c = (key[i] > last) && (key[i] < m);
      m = c ? key[i] : m;
    }
#pragma unroll
    for (int s = 1; s < 64; s <<= 1) {
      unsigned long long o = __shfl_xor(m, s, 64);
      m = (o < m) ? o : m;
    }
    if (lane == 0) idxo[(size_t)pg * NK + r] = gbase + (int)(m & 1023u);
    last = m;
  }
}

// ---------------------------------------------------------------------------
// FALLBACK kNN (used only if ws_size can't fit a 1-cloud distance matrix).
// ---------------------------------------------------------------------------
template <int DIM>
__global__ __launch_bounds__(256) void kknn(const float* __restrict__ x,
                                            const float* __restrict__ d2,
                                            int* __restrict__ idxo) {
  constexpr int STR = (DIM == 64) ? 68 : 4;
  __shared__ float smem[10240];
  float* tile = smem;
  float* dt = smem + 64 * STR;
  float* mD = smem;
  int* mI = (int*)(smem + 5120);

  const int tid = threadIdx.x;
  const int pt = tid & 63;
  const int qt = tid >> 6;
  const int cloud = blockIdx.x >> 4;
  const int blk = blockIdx.x & 15;
  const int p = cloud * 1024 + blk * 64 + pt;
  const int cbase = cloud * 1024;

  float xp[DIM];
#pragma unroll
  for (int d = 0; d < DIM; d++) xp[d] = x[(size_t)p * DIM + d];
  const float d2p = d2[p];

  float bd[NK];
  int bi[NK];
#pragma unroll
  for (int s = 0; s < NK; s++) {
    bd[s] = FLT_MAX;
    bi[s] = 0x7fffffff;
  }
  float wd = FLT_MAX;
  int wi = 0x7fffffff;
  int wsl = 0;

  for (int t = 0; t < 16; t++) {
    __syncthreads();
    if (tid < 64) {
#pragma unroll
      for (int d = 0; d < DIM; d++) tile[tid * STR + d] = x[(size_t)(cbase + t * 64 + tid) * DIM + d];
      dt[tid] = d2[cbase + t * 64 + tid];
    }
    __syncthreads();
    for (int jj = 0; jj < 16; jj++) {
      const int j = jj * 4 + qt;
      float s = 0.f;
#pragma unroll
      for (int d = 0; d < DIM; d++) s = fmaf(xp[d], tile[j * STR + d], s);
      const float dist = fmaf(-2.f, s, d2p + dt[j]);
      const int qg = cbase + t * 64 + j;
      const bool ins = (dist < wd) || (dist == wd && qg < wi);
      if (ins) {
#pragma unroll
        for (int sl = 0; sl < NK; sl++)
          if (sl == wsl) {
            bd[sl] = dist;
            bi[sl] = qg;
          }
        wd = bd[0];
        wi = bi[0];
        wsl = 0;
#pragma unroll
        for (int sl = 1; sl < NK; sl++) {
          const bool worse = (bd[sl] > wd) || (bd[sl] == wd && bi[sl] > wi);
          if (worse) {
            wd = bd[sl];
            wi = bi[sl];
            wsl = sl;
          }
        }
      }
    }
  }
  __syncthreads();
#pragma unroll
  for (int s = 0; s < NK; s++) {
    mD[pt * 80 + qt * 20 + s] = bd[s];
    mI[pt * 80 + qt * 20 + s] = bi[s];
  }
  __syncthreads();
  if (tid < 128) {
    const int pt2 = tid >> 1, h = tid & 1;
    const int base = pt2 * 80 + h * 40;
    float cd[40];
    int ci[40];
#pragma unroll
    for (int a = 0; a < 40; a++) {
      cd[a] = mD[base + a];
      ci[a] = mI[base + a];
    }
    int rank[40];
#pragma unroll
    for (int a = 0; a < 40; a++) rank[a] = 0;
#pragma unroll
    for (int a = 0; a < 40; a++)
#pragma unroll
      for (int b = a + 1; b < 40; b++) {
        const bool abet = (cd[a] < cd[b]) || (cd[a] == cd[b] && ci[a] < ci[b]);
        if (abet)
          rank[b]++;
        else
          rank[a]++;
      }
#pragma unroll
    for (int a = 0; a < 40; a++)
      if (rank[a] < NK) {
        mD[base + rank[a]] = cd[a];
        mI[base + rank[a]] = ci[a];
      }
  }
  __syncthreads();
  if (tid < 64) {
    const int base = tid * 80;
    float cd[40];
    int ci[40];
#pragma unroll
    for (int a = 0; a < 20; a++) {
      cd[a] = mD[base + a];
      ci[a] = mI[base + a];
      cd[20 + a] = mD[base + 40 + a];
      ci[20 + a] = mI[base + 40 + a];
    }
    int rank[40];
#pragma unroll
    for (int a = 0; a < 40; a++) rank[a] = 0;
#pragma unroll
    for (int a = 0; a < 40; a++)
#pragma unroll
      for (int b = a + 1; b < 40; b++) {
        const bool abet = (cd[a] < cd[b]) || (cd[a] == cd[b] && ci[a] < ci[b]);
        if (abet)
          rank[b]++;
        else
          rank[a]++;
      }
    const int po = cloud * 1024 + blk * 64 + tid;
#pragma unroll
    for (int a = 0; a < 40; a++)
      if (rank[a] < NK) idxo[(size_t)po * NK + rank[a]] = ci[a];
  }
}

// ---------------------------------------------------------------------------
__global__ void kzero(double* __restrict__ S) {
  if (threadIdx.x < 42) S[threadIdx.x] = 0.0;
}

// Edge-feature moments: S[0:6]=sum e, S[6:42]=sum e e^T  (e=[xi, xj-xi])
__global__ __launch_bounds__(256) void kstats(const float* __restrict__ pos,
                                              const int* __restrict__ idx,
                                              double* __restrict__ S) {
  int p = blockIdx.x * 256 + threadIdx.x;
  float xi0 = pos[p * 3], xi1 = pos[p * 3 + 1], xi2 = pos[p * 3 + 2];
  float s1[6];
  float s2[36];
#pragma unroll
  for (int a = 0; a < 6; a++) s1[a] = 0.f;
#pragma unroll
  for (int a = 0; a < 36; a++) s2[a] = 0.f;
  for (int k = 0; k < NK; k++) {
    int j = idx[p * NK + k];
    float e[6];
    e[0] = xi0;
    e[1] = xi1;
    e[2] = xi2;
    e[3] = pos[j * 3] - xi0;
    e[4] = pos[j * 3 + 1] - xi1;
    e[5] = pos[j * 3 + 2] - xi2;
#pragma unroll
    for (int a = 0; a < 6; a++) {
      s1[a] += e[a];
#pragma unroll
      for (int b = 0; b < 6; b++) s2[a * 6 + b] = fmaf(e[a], e[b], s2[a * 6 + b]);
    }
  }
  bool lead = (threadIdx.x & 63) == 0;
#pragma unroll
  for (int a = 0; a < 6; a++) {
    float v = s1[a];
#pragma unroll
    for (int m = 1; m < 64; m <<= 1) v += __shfl_xor(v, m, 64);
    if (lead) atomicAdd(&S[a], (double)v);
  }
#pragma unroll
  for (int a = 0; a < 36; a++) {
    float v = s2[a];
#pragma unroll
    for (int m = 1; m < 64; m <<= 1) v += __shfl_xor(v, m, 64);
    if (lead) atomicAdd(&S[6 + a], (double)v);
  }
}

// BN scale/shift from moments (exact in double)
__global__ void kbn(const double* __restrict__ S, const float* __restrict__ W1a,
                    const float* __restrict__ b1a, const float* __restrict__ g1,
                    const float* __restrict__ be1, float* __restrict__ ss) {
  int c = threadIdx.x;  // 64
  double w[6];
#pragma unroll
  for (int d = 0; d < 6; d++) w[d] = (double)W1a[d * 64 + c];
  double b = (double)b1a[c];
  const double invN = 1.0 / (double)((size_t)NPTS * NK);
  double m1 = 0.0;
#pragma unroll
  for (int d = 0; d < 6; d++) m1 += w[d] * S[d];
  m1 *= invN;
  double q = 0.0;
#pragma unroll
  for (int a = 0; a < 6; a++)
#pragma unroll
    for (int d = 0; d < 6; d++) q += w[a] * w[d] * S[6 + a * 6 + d];
  q *= invN;
  double mu = m1 + b;
  double eh2 = q + 2.0 * b * m1 + b * b;
  double var = eh2 - mu * mu;
  if (var < 0.0) var = 0.0;
  double inv = 1.0 / sqrt(var + 1e-5);
  double sc = (double)g1[c] * inv;
  ss[c] = (float)sc;
  ss[64 + c] = (float)((double)be1[c] - mu * sc);
}

// ---------------------------------------------------------------------------
// EdgeConv1 fused, GEMM-structured. Block = 8 points = 160 edges.
// Phase 1: Z[160][64] = relu(BN(edge)) into LDS (wave = 2 pts, lane = chan;
//          neighbor pos loads are scalar via readfirstlane).
// Phase 2: Y = Z @ W1b as a 5x8-register-tile GEMM (A,B both LDS, stride 68).
// Phase 3: x1[p][c] = max_k Y[p*20+k][c] + b1b[c].
// LDS-instr count ~260 b128/wave vs ~5120 in the naive broadcast version.
// ---------------------------------------------------------------------------
__global__ __launch_bounds__(256) void kec1(const float* __restrict__ pos,
                                            const int* __restrict__ idx,
                                            const float* __restrict__ ss,
                                            const float* __restrict__ W1a,
                                            const float* __restrict__ b1a,
                                            const float* __restrict__ W1b,
                                            const float* __restrict__ b1b,
                                            float* __restrict__ x1) {
  __shared__ float Z[160 * 68];   // 43520 B, Y overwrites it later
  __shared__ float BW[64 * 68];   // 17408 B
  __shared__ int idxs[160];       // 640 B
  const int tid = threadIdx.x;
  const int lane = tid & 63;
  const int w = tid >> 6;
  const int p0 = blockIdx.x * 8;

  // stage W1b (64x64) -> BW (stride 68)
#pragma unroll
  for (int r = 0; r < 4; r++) {
    const int id = r * 256 + tid;  // 1024 float4
    const int d = id >> 4, c4 = (id & 15) * 4;
    const float4 w4 = *(const float4*)&W1b[d * 64 + c4];
    *(float4*)&BW[d * 68 + c4] = w4;
  }
  if (tid < 160) idxs[tid] = idx[(size_t)p0 * NK + tid];

  // per-lane (channel) parameters
  float wdf[3], wbt[3];
#pragma unroll
  for (int d = 0; d < 3; d++) {
    const float top = W1a[d * 64 + lane];
    const float bot = W1a[(3 + d) * 64 + lane];
    wdf[d] = top - bot;
    wbt[d] = bot;
  }
  const float b1 = b1a[lane];
  const float sc = ss[lane];
  const float sh = ss[64 + lane];
  __syncthreads();

  // phase 1: Z rows (wave w -> local points 2w, 2w+1)
#pragma unroll
  for (int pp = 0; pp < 2; pp++) {
    const int pl = w * 2 + pp;
    const int p = p0 + pl;
    const float xi0 = pos[p * 3], xi1 = pos[p * 3 + 1], xi2 = pos[p * 3 + 2];
    const float pu = fmaf(xi2, wdf[2], fmaf(xi1, wdf[1], fmaf(xi0, wdf[0], b1)));
    for (int k = 0; k < NK; k++) {
      const int j = __builtin_amdgcn_readfirstlane(idxs[pl * NK + k]);
      const float xj0 = pos[j * 3], xj1 = pos[j * 3 + 1], xj2 = pos[j * 3 + 2];
      const float pv = fmaf(xj2, wbt[2], fmaf(xj1, wbt[1], xj0 * wbt[0]));
      Z[(pl * NK + k) * 68 + lane] = fmaxf(fmaf(pu + pv, sc, sh), 0.f);
    }
  }
  __syncthreads();

  // phase 2: GEMM Y(160x64) = Z(160x64) @ BW(64x64); thread tile 5 rows x 8 ch
  const int tc = tid & 7;   // channel group
  const int tm = tid >> 3;  // 0..31, rows tm + 32*i
  float acc[5][8];
#pragma unroll
  for (int i = 0; i < 5; i++)
#pragma unroll
    for (int n = 0; n < 8; n++) acc[i][n] = 0.f;

#pragma unroll
  for (int d4 = 0; d4 < 16; d4++) {
    float b[4][8];
#pragma unroll
    for (int r = 0; r < 4; r++) {
      *(float4*)&b[r][0] = *(const float4*)&BW[(d4 * 4 + r) * 68 + tc * 8];
      *(float4*)&b[r][4] = *(const float4*)&BW[(d4 * 4 + r) * 68 + tc * 8 + 4];
    }
#pragma unroll
    for (int i = 0; i < 5; i++) {
      float a[4];
      *(float4*)&a[0] = *(const float4*)&Z[(tm + 32 * i) * 68 + d4 * 4];
#pragma unroll
      for (int r = 0; r < 4; r++)
#pragma unroll
        for (int n = 0; n < 8; n++) acc[i][n] = fmaf(a[r], b[r][n], acc[i][n]);
    }
  }
  __syncthreads();  // all Z reads done; overwrite with Y

#pragma unroll
  for (int i = 0; i < 5; i++) {
    *(float4*)&Z[(tm + 32 * i) * 68 + tc * 8] = *(const float4*)&acc[i][0];
    *(float4*)&Z[(tm + 32 * i) * 68 + tc * 8 + 4] = *(const float4*)&acc[i][4];
  }
  __syncthreads();

  // phase 3: per (point, channel) max over 20 edge rows, + b1b
#pragma unroll
  for (int h = 0; h < 2; h++) {
    const int pc = h * 256 + tid;  // 512 pairs
    const int pl = pc >> 6, c = pc & 63;
    float m = -FLT_MAX;
#pragma unroll
    for (int k = 0; k < NK; k++) m = fmaxf(m, Z[(pl * NK + k) * 68 + c]);
    x1[(size_t)(p0 + pl) * 64 + c] = m + b1b[c];
  }
}

// v[j,c] = x1_j . W2[64+d][c]
__global__ __launch_bounds__(256) void kv(const float* __restrict__ x1,
                                          const float* __restrict__ W2,
                                          float* __restrict__ v) {
  const int c = threadIdx.x & 127;
  const int sub = threadIdx.x >> 7;
  float wv[64];
#pragma unroll
  for (int d = 0; d < 64; d++) wv[d] = W2[(64 + d) * 128 + c];
  const int pbase = blockIdx.x * 64 + sub * 32;
  for (int i = 0; i < 32; i++) {
    const int p = pbase + i;
    const float4* xr = (const float4*)(x1 + (size_t)p * 64);
    float a0 = 0.f, a1 = 0.f;
#pragma unroll
    for (int dq = 0; dq < 16; dq++) {
      float4 xv = xr[dq];
      a0 = fmaf(xv.x, wv[dq * 4 + 0], a0);
      a1 = fmaf(xv.y, wv[dq * 4 + 1], a1);
      a0 = fmaf(xv.z, wv[dq * 4 + 2], a0);
      a1 = fmaf(xv.w, wv[dq * 4 + 3], a1);
    }
    v[(size_t)p * 128 + c] = a0 + a1;
  }
}

// Bc (192x128) and const bias cb (128)
__global__ __launch_bounds__(256) void kprep(const float* __restrict__ W2,
                                             const float* __restrict__ Wl,
                                             const float* __restrict__ b2,
                                             const float* __restrict__ bl,
                                             float* __restrict__ Bc,
                                             float* __restrict__ cb) {
  const int t = blockIdx.x * 256 + threadIdx.x;  // 8192
  const int d = t >> 7, c = t & 127;
  float s = Wl[d * 128 + c];
  for (int e = 0; e < 128; e++)
    s = fmaf(W2[d * 128 + e] - W2[(64 + d) * 128 + e], Wl[(64 + e) * 128 + c], s);
  Bc[d * 128 + c] = s;
  Bc[(64 + 2 * d) * 128 + c] = Wl[(64 + 2 * d) * 128 + c];
  Bc[(64 + 2 * d + 1) * 128 + c] = Wl[(64 + 2 * d + 1) * 128 + c];
  if (d == 0) {
    float sb = bl[c];
    for (int e = 0; e < 128; e++) sb = fmaf(b2[e], Wl[(64 + e) * 128 + c], sb);
    cb[c] = sb;
  }
}

// Final fused: AT = [x1^T ; maxgather(v)^T], GEMM with Bc, per-tile max.
#define ATS 72
#define BSS 132
__global__ __launch_bounds__(256) void kgemm(const float* __restrict__ x1,
                                             const float* __restrict__ v,
                                             const int* __restrict__ idx,
                                             const float* __restrict__ Bc,
                                             float* __restrict__ partial) {
  __shared__ float AT[192 * ATS];
  __shared__ float BS[16 * BSS];
  int* idxs = (int*)BS;
  const int tid = threadIdx.x;
  const int cloud = blockIdx.x >> 4;
  const int mb = blockIdx.x & 15;
  const int pbase = cloud * 1024 + mb * 64;

#pragma unroll
  for (int r = 0; r < 5; r++) {
    int id = r * 256 + tid;
    idxs[id] = idx[(size_t)pbase * NK + id];
  }
#pragma unroll
  for (int r = 0; r < 16; r++) {
    int id = r * 256 + tid;
    int m = id >> 6, k = id & 63;
    AT[k * ATS + m] = x1[(size_t)(pbase + m) * 64 + k];
  }
  __syncthreads();
#pragma unroll
  for (int r = 0; r < 32; r++) {
    int id = r * 256 + tid;
    int m = id >> 7, kk = id & 127;
    const int* ip = &idxs[m * NK];
    float mx = -FLT_MAX;
#pragma unroll
    for (int k = 0; k < NK; k++) mx = fmaxf(mx, v[(size_t)ip[k] * 128 + kk]);
    AT[(64 + kk) * ATS + m] = mx;
  }
  __syncthreads();

  const int tr = tid >> 4, tc = tid & 15;
  float acc[4][8];
#pragma unroll
  for (int i = 0; i < 4; i++)
#pragma unroll
    for (int n = 0; n < 8; n++) acc[i][n] = 0.f;
  for (int kc = 0; kc < 12; kc++) {
#pragma unroll
    for (int r = 0; r < 8; r++) {
      int id = r * 256 + tid;
      int row = id >> 7, col = id & 127;
      BS[row * BSS + col] = Bc[(size_t)(kc * 16 + row) * 128 + col];
    }
    __syncthreads();
#pragma unroll
    for (int k = 0; k < 16; k++) {
      int kg = kc * 16 + k;
      float4 a = *(const float4*)&AT[kg * ATS + tr * 4];
      float4 b0 = *(const float4*)&BS[k * BSS + tc * 8];
      float4 b1 = *(const float4*)&BS[k * BSS + tc * 8 + 4];
      float av[4] = {a.x, a.y, a.z, a.w};
      float bv[8] = {b0.x, b0.y, b0.z, b0.w, b1.x, b1.y, b1.z, b1.w};
#pragma unroll
      for (int i = 0; i < 4; i++)
#pragma unroll
        for (int n = 0; n < 8; n++) acc[i][n] = fmaf(av[i], bv[n], acc[i][n]);
    }
    __syncthreads();
  }
#pragma unroll
  for (int n = 0; n < 8; n++) {
    float m4 = fmaxf(fmaxf(acc[0][n], acc[1][n]), fmaxf(acc[2][n], acc[3][n]));
    BS[tr * BSS + tc * 8 + n] = m4;
  }
  __syncthreads();
  if (tid < 128) {
    float m = -FLT_MAX;
#pragma unroll
    for (int rr = 0; rr < 16; rr++) m = fmaxf(m, BS[rr * BSS + tid]);
    partial[(size_t)blockIdx.x * 128 + tid] = m;
  }
}

__global__ __launch_bounds__(256) void kred(const float* __restrict__ partial,
                                            const float* __restrict__ cb,
                                            float* __restrict__ out) {
  int t = blockIdx.x * 256 + threadIdx.x;  // 4096
  int b = t >> 7, c = t & 127;
  float m = -FLT_MAX;
#pragma unroll
  for (int mb = 0; mb < 16; mb++) m = fmaxf(m, partial[(size_t)(b * 16 + mb) * 128 + c]);
  out[t] = m + cb[c];
}

// ---------------------------------------------------------------------------
extern "C" void kernel_launch(void* const* d_in, const int* in_sizes, int n_in,
                              void* d_out, int out_size, void* d_ws, size_t ws_size,
                              hipStream_t stream) {
  const float* pos = (const float*)d_in[0];
  const float* W1a = (const float*)d_in[1];
  const float* b1a = (const float*)d_in[2];
  const float* g1 = (const float*)d_in[3];
  const float* be1 = (const float*)d_in[4];
  const float* W1b = (const float*)d_in[5];
  const float* b1b = (const float*)d_in[6];
  const float* W2 = (const float*)d_in[7];
  const float* b2 = (const float*)d_in[8];
  const float* Wl = (const float*)d_in[9];
  const float* bl = (const float*)d_in[10];
  float* out = (float*)d_out;

  // Base workspace (floats): 7,070,080 = 28.3 MB. D-matrix chunk after it.
  float* ws = (float*)d_ws;
  float* x1 = ws;                       // 2,097,152
  float* v = ws + 2097152;              // 4,194,304
  int* idx = (int*)(ws + 6291456);      // 655,360
  float* d2b = ws + 6946816;            // 32,768
  double* S = (double*)(ws + 6979584);  // 42 doubles (84 slots)
  float* Bc = ws + 6979712;             // 24,576
  float* cb = ws + 7004288;             // 128
  float* ss = ws + 7004416;             // 128
  float* partial = ws + 7004544;        // 65,536 -> end 7,070,080
  const size_t base = 7070080;
  float* D = ws + base;

  if (ws_size < base * sizeof(float)) return;  // fail soft

  // cloud-chunk size for the distance matrix (4 MB per cloud)
  size_t avail = ws_size / sizeof(float) - base;
  int nc = 0;
  for (int c = 32; c >= 1; c >>= 1)
    if ((size_t)c * 1024 * 1024 <= avail) {
      nc = c;
      break;
    }

  // --- layer 1: kNN on pos (3D) ---
  kd2<<<128, 256, 0, stream>>>(pos, 3, d2b);
  if (nc > 0) {
    for (int c0 = 0; c0 < NB; c0 += nc) {
      kdist<3><<<nc * 64, 256, 0, stream>>>(pos, d2b, c0, D);
      kselect<<<nc * 256, 256, 0, stream>>>(D, c0, idx);
    }
  } else {
    kknn<3><<<512, 256, 0, stream>>>(pos, d2b, idx);
  }

  // --- EdgeConv1 (analytic BN via exact 6-dim moments) ---
  kzero<<<1, 64, 0, stream>>>(S);
  kstats<<<128, 256, 0, stream>>>(pos, idx, S);
  kbn<<<1, 64, 0, stream>>>(S, W1a, b1a, g1, be1, ss);
  kec1<<<4096, 256, 0, stream>>>(pos, idx, ss, W1a, b1a, W1b, b1b, x1);

  // --- layer 2: kNN on x1 (64D) ---
  kd2<<<128, 256, 0, stream>>>(x1, 64, d2b);
  if (nc > 0) {
    for (int c0 = 0; c0 < NB; c0 += nc) {
      kdist<64><<<nc * 64, 256, 0, stream>>>(x1, d2b, c0, D);
      kselect<<<nc * 256, 256, 0, stream>>>(D, c0, idx);
    }
  } else {
    kknn<64><<<512, 256, 0, stream>>>(x1, d2b, idx);
  }

  // --- EdgeConv2 factored + fused final linear + pool ---
  kv<<<512, 256, 0, stream>>>(x1, W2, v);
  kprep<<<32, 256, 0, stream>>>(W2, Wl, b2, bl, Bc, cb);
  kgemm<<<512, 256, 0, stream>>>(x1, v, idx, Bc, partial);
  kred<<<16, 256, 0, stream>>>(partial, cb, out);
}

// Round 5
// 559.537 us; speedup vs baseline: 2.5417x; 1.2014x over previous
//
#include <hip/hip_runtime.h>
#include <cfloat>
#include <cstdint>

#define NB 32
#define NP 1024
#define NK 20
#define NPTS 32768  // NB*NP

// ---------------------------------------------------------------------------
// d2[p] = sum x^2, SINGLE sequential FMA chain (order-matched with kdist's
// per-acc chain so diagonal dist = fmaf(-2,d2p,2*d2p) = exact 0).
// ---------------------------------------------------------------------------
__global__ __launch_bounds__(256) void kd2(const float* __restrict__ x, int dim,
                                           float* __restrict__ d2) {
  int p = blockIdx.x * 256 + threadIdx.x;
  if (p >= NPTS) return;
  if (dim == 64) {
    const float4* xr = (const float4*)(x + (size_t)p * 64);
    float s = 0.f;
#pragma unroll
    for (int dq = 0; dq < 16; dq++) {
      float4 v = xr[dq];
      s = fmaf(v.x, v.x, s);
      s = fmaf(v.y, v.y, s);
      s = fmaf(v.z, v.z, s);
      s = fmaf(v.w, v.w, s);
    }
    d2[p] = s;
  } else {
    float s = 0.f;
#pragma unroll
    for (int d = 0; d < 3; d++) {
      float v = x[p * 3 + d];
      s = fmaf(v, v, s);
    }
    d2[p] = s;
  }
}

// ---------------------------------------------------------------------------
// kdist: full per-cloud distance matrix, 128x128 tile per block.
// ---------------------------------------------------------------------------
template <int DIM>
__global__ __launch_bounds__(256) void kdist(const float* __restrict__ x,
                                             const float* __restrict__ d2,
                                             int c0, float* __restrict__ D) {
  constexpr int KC = (DIM == 64) ? 32 : 3;
  __shared__ float As[KC][132];
  __shared__ float Bs[KC][132];
  const int tid = threadIdx.x;
  const int cloud = blockIdx.x >> 6;  // within chunk
  const int t = blockIdx.x & 63;
  const int tr0 = (t >> 3) * 128, tc0 = (t & 7) * 128;
  const int cb = (c0 + cloud) * 1024;
  const int tr = tid >> 4, tc = tid & 15;

  float acc[8][8];
#pragma unroll
  for (int i = 0; i < 8; i++)
#pragma unroll
    for (int j = 0; j < 8; j++) acc[i][j] = 0.f;

  for (int kc = 0; kc < DIM; kc += KC) {
    __syncthreads();
    if constexpr (DIM == 64) {
      const int row = tid >> 1, seg = tid & 1;
      const float4* sa = (const float4*)(x + (size_t)(cb + tr0 + row) * 64 + kc + seg * 16);
      const float4* sb = (const float4*)(x + (size_t)(cb + tc0 + row) * 64 + kc + seg * 16);
#pragma unroll
      for (int i = 0; i < 4; i++) {
        float4 va = sa[i];
        float4 vb = sb[i];
        const int k0 = seg * 16 + i * 4;
        As[k0 + 0][row] = va.x;
        As[k0 + 1][row] = va.y;
        As[k0 + 2][row] = va.z;
        As[k0 + 3][row] = va.w;
        Bs[k0 + 0][row] = vb.x;
        Bs[k0 + 1][row] = vb.y;
        Bs[k0 + 2][row] = vb.z;
        Bs[k0 + 3][row] = vb.w;
      }
    } else {
      if (tid < 128) {
#pragma unroll
        for (int d = 0; d < 3; d++) {
          As[d][tid] = x[(size_t)(cb + tr0 + tid) * 3 + d];
          Bs[d][tid] = x[(size_t)(cb + tc0 + tid) * 3 + d];
        }
      }
    }
    __syncthreads();
#pragma unroll
    for (int k = 0; k < KC; k++) {
      float a[8], b[8];
      *(float4*)&a[0] = *(const float4*)&As[k][tr * 8];
      *(float4*)&a[4] = *(const float4*)&As[k][tr * 8 + 4];
      *(float4*)&b[0] = *(const float4*)&Bs[k][tc * 8];
      *(float4*)&b[4] = *(const float4*)&Bs[k][tc * 8 + 4];
#pragma unroll
      for (int i = 0; i < 8; i++)
#pragma unroll
        for (int j = 0; j < 8; j++) acc[i][j] = fmaf(a[i], b[j], acc[i][j]);
    }
  }
  float d2r[8], d2c[8];
#pragma unroll
  for (int i = 0; i < 8; i++) d2r[i] = d2[cb + tr0 + tr * 8 + i];
#pragma unroll
  for (int j = 0; j < 8; j++) d2c[j] = d2[cb + tc0 + tc * 8 + j];
#pragma unroll
  for (int i = 0; i < 8; i++) {
    float o[8];
#pragma unroll
    for (int j = 0; j < 8; j++) o[j] = fmaf(-2.f, acc[i][j], d2r[i] + d2c[j]);
    float* dst = &D[(size_t)(cloud * 1024 + tr0 + tr * 8 + i) * 1024 + tc0 + tc * 8];
    *(float4*)&dst[0] = *(const float4*)&o[0];
    *(float4*)&dst[4] = *(const float4*)&o[4];
  }
}

// ---------------------------------------------------------------------------
// kselect v2: exact top-20 via pivot selection. Keys = (sortable_dist<<10)|q,
// all distinct -> a pivot with count in [20,63] always exists. Binary search
// (seeded by butterfly min/max) ~12 iters; then prefix-compact candidates to
// per-wave LDS; one broadcast rank pass emits the exact ascending top-20.
// ---------------------------------------------------------------------------
__global__ __launch_bounds__(256) void kselect(const float* __restrict__ D,
                                               int c0, int* __restrict__ idxo) {
  __shared__ unsigned long long lw[4][64];
  const int lane = threadIdx.x & 63;
  const int sub = threadIdx.x >> 6;
  const int pchunk = blockIdx.x * 4 + sub;  // point within chunk
  const int pg = c0 * 1024 + pchunk;        // global point
  const int gbase = (pg >> 10) << 10;       // cloud base (global)

  unsigned long long key[16];
  const float4* dr = (const float4*)(D + (size_t)pchunk * 1024 + lane * 4);
#pragma unroll
  for (int i = 0; i < 4; i++) {
    float4 d4 = dr[i * 64];  // q = i*256 + lane*4 ..+3
    float dv[4] = {d4.x, d4.y, d4.z, d4.w};
#pragma unroll
    for (int j = 0; j < 4; j++) {
      unsigned int u = __float_as_uint(dv[j]);
      u ^= (((int)u >> 31) | 0x80000000u);  // sortable transform
      key[i * 4 + j] = ((unsigned long long)u << 10) | (unsigned)(i * 256 + lane * 4 + j);
    }
  }

  // seed [lo,hi] with data min / max+1 (tight range -> fewer iterations)
  unsigned long long mn = key[0], mx = key[0];
#pragma unroll
  for (int i = 1; i < 16; i++) {
    mn = key[i] < mn ? key[i] : mn;
    mx = key[i] > mx ? key[i] : mx;
  }
#pragma unroll
  for (int s = 1; s < 64; s <<= 1) {
    unsigned long long a = __shfl_xor(mn, s, 64);
    unsigned long long b = __shfl_xor(mx, s, 64);
    mn = a < mn ? a : mn;
    mx = b > mx ? b : mx;
  }
  unsigned long long lo = mn, hi = mx + 1, mid = hi;
  // invariant: count(<lo) < 20, count(<hi) > 63 (hi = max+1 -> 1024)
  bool found = false;
  for (int it = 0; it < 48 && !found; ++it) {
    unsigned long long m2 = lo + ((hi - lo) >> 1);
    int cnt = 0;
#pragma unroll
    for (int i = 0; i < 16; i++) cnt += (key[i] < m2) ? 1 : 0;
#pragma unroll
    for (int s = 1; s < 64; s <<= 1) cnt += __shfl_xor(cnt, s, 64);
    if (cnt < 20)
      lo = m2;
    else if (cnt > 63)
      hi = m2;
    else {
      mid = m2;
      found = true;
    }
  }
  // (found guaranteed: keys distinct => window non-empty; mid=hi fallback safe)

  // per-lane candidate mask for final pivot
  unsigned int mask = 0;
#pragma unroll
  for (int i = 0; i < 16; i++) mask |= (key[i] < mid) ? (1u << i) : 0u;
  const int lc = __popc(mask);
  int x = lc;
#pragma unroll
  for (int s = 1; s < 64; s <<= 1) {
    int y = __shfl_up(x, s, 64);
    if (lane >= s) x += y;
  }
  int off = x - lc;                                // exclusive prefix
  const int ctot = __shfl(x, 63, 64);              // total candidates
  const int c = ctot < 64 ? ctot : 64;             // cap (normal: 20..63)
  unsigned long long* w = lw[sub];
#pragma unroll
  for (int i = 0; i < 16; i++) {
    if ((mask & (1u << i)) && off < 64) {
      w[off] = key[i];
      off++;
    }
  }
  __builtin_amdgcn_wave_barrier();

  const unsigned long long K = w[lane < c ? lane : 0];
  int rank = 0;
  for (int m = 0; m < c; m++) {
    const unsigned long long Km = w[m];  // broadcast read
    rank += (K > Km) ? 1 : 0;
  }
  if (lane < c && rank < NK)
    idxo[(size_t)pg * NK + rank] = gbase + (int)(K & 1023u);
}

// ---------------------------------------------------------------------------
// FALLBACK kNN (used only if ws_size can't fit a 1-cloud distance matrix).
// ---------------------------------------------------------------------------
template <int DIM>
__global__ __launch_bounds__(256) void kknn(const float* __restrict__ x,
                                            const float* __restrict__ d2,
                                            int* __restrict__ idxo) {
  constexpr int STR = (DIM == 64) ? 68 : 4;
  __shared__ float smem[10240];
  float* tile = smem;
  float* dt = smem + 64 * STR;
  float* mD = smem;
  int* mI = (int*)(smem + 5120);

  const int tid = threadIdx.x;
  const int pt = tid & 63;
  const int qt = tid >> 6;
  const int cloud = blockIdx.x >> 4;
  const int blk = blockIdx.x & 15;
  const int p = cloud * 1024 + blk * 64 + pt;
  const int cbase = cloud * 1024;

  float xp[DIM];
#pragma unroll
  for (int d = 0; d < DIM; d++) xp[d] = x[(size_t)p * DIM + d];
  const float d2p = d2[p];

  float bd[NK];
  int bi[NK];
#pragma unroll
  for (int s = 0; s < NK; s++) {
    bd[s] = FLT_MAX;
    bi[s] = 0x7fffffff;
  }
  float wd = FLT_MAX;
  int wi = 0x7fffffff;
  int wsl = 0;

  for (int t = 0; t < 16; t++) {
    __syncthreads();
    if (tid < 64) {
#pragma unroll
      for (int d = 0; d < DIM; d++) tile[tid * STR + d] = x[(size_t)(cbase + t * 64 + tid) * DIM + d];
      dt[tid] = d2[cbase + t * 64 + tid];
    }
    __syncthreads();
    for (int jj = 0; jj < 16; jj++) {
      const int j = jj * 4 + qt;
      float s = 0.f;
#pragma unroll
      for (int d = 0; d < DIM; d++) s = fmaf(xp[d], tile[j * STR + d], s);
      const float dist = fmaf(-2.f, s, d2p + dt[j]);
      const int qg = cbase + t * 64 + j;
      const bool ins = (dist < wd) || (dist == wd && qg < wi);
      if (ins) {
#pragma unroll
        for (int sl = 0; sl < NK; sl++)
          if (sl == wsl) {
            bd[sl] = dist;
            bi[sl] = qg;
          }
        wd = bd[0];
        wi = bi[0];
        wsl = 0;
#pragma unroll
        for (int sl = 1; sl < NK; sl++) {
          const bool worse = (bd[sl] > wd) || (bd[sl] == wd && bi[sl] > wi);
          if (worse) {
            wd = bd[sl];
            wi = bi[sl];
            wsl = sl;
          }
        }
      }
    }
  }
  __syncthreads();
#pragma unroll
  for (int s = 0; s < NK; s++) {
    mD[pt * 80 + qt * 20 + s] = bd[s];
    mI[pt * 80 + qt * 20 + s] = bi[s];
  }
  __syncthreads();
  if (tid < 128) {
    const int pt2 = tid >> 1, h = tid & 1;
    const int base = pt2 * 80 + h * 40;
    float cd[40];
    int ci[40];
#pragma unroll
    for (int a = 0; a < 40; a++) {
      cd[a] = mD[base + a];
      ci[a] = mI[base + a];
    }
    int rank[40];
#pragma unroll
    for (int a = 0; a < 40; a++) rank[a] = 0;
#pragma unroll
    for (int a = 0; a < 40; a++)
#pragma unroll
      for (int b = a + 1; b < 40; b++) {
        const bool abet = (cd[a] < cd[b]) || (cd[a] == cd[b] && ci[a] < ci[b]);
        if (abet)
          rank[b]++;
        else
          rank[a]++;
      }
#pragma unroll
    for (int a = 0; a < 40; a++)
      if (rank[a] < NK) {
        mD[base + rank[a]] = cd[a];
        mI[base + rank[a]] = ci[a];
      }
  }
  __syncthreads();
  if (tid < 64) {
    const int base = tid * 80;
    float cd[40];
    int ci[40];
#pragma unroll
    for (int a = 0; a < 20; a++) {
      cd[a] = mD[base + a];
      ci[a] = mI[base + a];
      cd[20 + a] = mD[base + 40 + a];
      ci[20 + a] = mI[base + 40 + a];
    }
    int rank[40];
#pragma unroll
    for (int a = 0; a < 40; a++) rank[a] = 0;
#pragma unroll
    for (int a = 0; a < 40; a++)
#pragma unroll
      for (int b = a + 1; b < 40; b++) {
        const bool abet = (cd[a] < cd[b]) || (cd[a] == cd[b] && ci[a] < ci[b]);
        if (abet)
          rank[b]++;
        else
          rank[a]++;
      }
    const int po = cloud * 1024 + blk * 64 + tid;
#pragma unroll
    for (int a = 0; a < 40; a++)
      if (rank[a] < NK) idxo[(size_t)po * NK + rank[a]] = ci[a];
  }
}

// ---------------------------------------------------------------------------
// Edge moments, ATOMIC-FREE: wave butterfly -> LDS cross-wave -> per-block
// partial (double). kbn reduces the 128 partials.
// ---------------------------------------------------------------------------
__global__ __launch_bounds__(256) void kstats(const float* __restrict__ pos,
                                              const int* __restrict__ idx,
                                              double* __restrict__ Spart) {
  __shared__ float red[4][42];
  const int tid = threadIdx.x;
  const int w = tid >> 6;
  int p = blockIdx.x * 256 + tid;
  float xi0 = pos[p * 3], xi1 = pos[p * 3 + 1], xi2 = pos[p * 3 + 2];
  float s1[6];
  float s2[36];
#pragma unroll
  for (int a = 0; a < 6; a++) s1[a] = 0.f;
#pragma unroll
  for (int a = 0; a < 36; a++) s2[a] = 0.f;
  for (int k = 0; k < NK; k++) {
    int j = idx[p * NK + k];
    float e[6];
    e[0] = xi0;
    e[1] = xi1;
    e[2] = xi2;
    e[3] = pos[j * 3] - xi0;
    e[4] = pos[j * 3 + 1] - xi1;
    e[5] = pos[j * 3 + 2] - xi2;
#pragma unroll
    for (int a = 0; a < 6; a++) {
      s1[a] += e[a];
#pragma unroll
      for (int b = 0; b < 6; b++) s2[a * 6 + b] = fmaf(e[a], e[b], s2[a * 6 + b]);
    }
  }
#pragma unroll
  for (int a = 0; a < 6; a++) {
#pragma unroll
    for (int m = 1; m < 64; m <<= 1) s1[a] += __shfl_xor(s1[a], m, 64);
  }
#pragma unroll
  for (int a = 0; a < 36; a++) {
#pragma unroll
    for (int m = 1; m < 64; m <<= 1) s2[a] += __shfl_xor(s2[a], m, 64);
  }
  if ((tid & 63) == 0) {
#pragma unroll
    for (int a = 0; a < 6; a++) red[w][a] = s1[a];
#pragma unroll
    for (int a = 0; a < 36; a++) red[w][6 + a] = s2[a];
  }
  __syncthreads();
  if (tid < 42) {
    double t = (double)red[0][tid] + (double)red[1][tid] + (double)red[2][tid] +
               (double)red[3][tid];
    Spart[(size_t)blockIdx.x * 42 + tid] = t;
  }
}

// BN scale/shift from moments (reduce 128 partials, then exact in double)
__global__ void kbn(const double* __restrict__ Spart, const float* __restrict__ W1a,
                    const float* __restrict__ b1a, const float* __restrict__ g1,
                    const float* __restrict__ be1, float* __restrict__ ss) {
  __shared__ double S[42];
  int c = threadIdx.x;  // 64
  if (c < 42) {
    double t = 0.0;
    for (int b = 0; b < 128; b++) t += Spart[(size_t)b * 42 + c];
    S[c] = t;
  }
  __syncthreads();
  double w[6];
#pragma unroll
  for (int d = 0; d < 6; d++) w[d] = (double)W1a[d * 64 + c];
  double b = (double)b1a[c];
  const double invN = 1.0 / (double)((size_t)NPTS * NK);
  double m1 = 0.0;
#pragma unroll
  for (int d = 0; d < 6; d++) m1 += w[d] * S[d];
  m1 *= invN;
  double q = 0.0;
#pragma unroll
  for (int a = 0; a < 6; a++)
#pragma unroll
    for (int d = 0; d < 6; d++) q += w[a] * w[d] * S[6 + a * 6 + d];
  q *= invN;
  double mu = m1 + b;
  double eh2 = q + 2.0 * b * m1 + b * b;
  double var = eh2 - mu * mu;
  if (var < 0.0) var = 0.0;
  double inv = 1.0 / sqrt(var + 1e-5);
  double sc = (double)g1[c] * inv;
  ss[c] = (float)sc;
  ss[64 + c] = (float)((double)be1[c] - mu * sc);
}

// ---------------------------------------------------------------------------
// EdgeConv1 fused, GEMM-structured. Block = 8 points = 160 edges.
// ---------------------------------------------------------------------------
__global__ __launch_bounds__(256) void kec1(const float* __restrict__ pos,
                                            const int* __restrict__ idx,
                                            const float* __restrict__ ss,
                                            const float* __restrict__ W1a,
                                            const float* __restrict__ b1a,
                                            const float* __restrict__ W1b,
                                            const float* __restrict__ b1b,
                                            float* __restrict__ x1) {
  __shared__ float Z[160 * 68];   // 43520 B, Y overwrites it later
  __shared__ float BW[64 * 68];   // 17408 B
  __shared__ int idxs[160];       // 640 B
  const int tid = threadIdx.x;
  const int lane = tid & 63;
  const int w = tid >> 6;
  const int p0 = blockIdx.x * 8;

#pragma unroll
  for (int r = 0; r < 4; r++) {
    const int id = r * 256 + tid;  // 1024 float4
    const int d = id >> 4, c4 = (id & 15) * 4;
    const float4 w4 = *(const float4*)&W1b[d * 64 + c4];
    *(float4*)&BW[d * 68 + c4] = w4;
  }
  if (tid < 160) idxs[tid] = idx[(size_t)p0 * NK + tid];

  float wdf[3], wbt[3];
#pragma unroll
  for (int d = 0; d < 3; d++) {
    const float top = W1a[d * 64 + lane];
    const float bot = W1a[(3 + d) * 64 + lane];
    wdf[d] = top - bot;
    wbt[d] = bot;
  }
  const float b1 = b1a[lane];
  const float sc = ss[lane];
  const float sh = ss[64 + lane];
  __syncthreads();

#pragma unroll
  for (int pp = 0; pp < 2; pp++) {
    const int pl = w * 2 + pp;
    const int p = p0 + pl;
    const float xi0 = pos[p * 3], xi1 = pos[p * 3 + 1], xi2 = pos[p * 3 + 2];
    const float pu = fmaf(xi2, wdf[2], fmaf(xi1, wdf[1], fmaf(xi0, wdf[0], b1)));
    for (int k = 0; k < NK; k++) {
      const int j = __builtin_amdgcn_readfirstlane(idxs[pl * NK + k]);
      const float xj0 = pos[j * 3], xj1 = pos[j * 3 + 1], xj2 = pos[j * 3 + 2];
      const float pv = fmaf(xj2, wbt[2], fmaf(xj1, wbt[1], xj0 * wbt[0]));
      Z[(pl * NK + k) * 68 + lane] = fmaxf(fmaf(pu + pv, sc, sh), 0.f);
    }
  }
  __syncthreads();

  const int tc = tid & 7;
  const int tm = tid >> 3;
  float acc[5][8];
#pragma unroll
  for (int i = 0; i < 5; i++)
#pragma unroll
    for (int n = 0; n < 8; n++) acc[i][n] = 0.f;

#pragma unroll
  for (int d4 = 0; d4 < 16; d4++) {
    float b[4][8];
#pragma unroll
    for (int r = 0; r < 4; r++) {
      *(float4*)&b[r][0] = *(const float4*)&BW[(d4 * 4 + r) * 68 + tc * 8];
      *(float4*)&b[r][4] = *(const float4*)&BW[(d4 * 4 + r) * 68 + tc * 8 + 4];
    }
#pragma unroll
    for (int i = 0; i < 5; i++) {
      float a[4];
      *(float4*)&a[0] = *(const float4*)&Z[(tm + 32 * i) * 68 + d4 * 4];
#pragma unroll
      for (int r = 0; r < 4; r++)
#pragma unroll
        for (int n = 0; n < 8; n++) acc[i][n] = fmaf(a[r], b[r][n], acc[i][n]);
    }
  }
  __syncthreads();

#pragma unroll
  for (int i = 0; i < 5; i++) {
    *(float4*)&Z[(tm + 32 * i) * 68 + tc * 8] = *(const float4*)&acc[i][0];
    *(float4*)&Z[(tm + 32 * i) * 68 + tc * 8 + 4] = *(const float4*)&acc[i][4];
  }
  __syncthreads();

#pragma unroll
  for (int h = 0; h < 2; h++) {
    const int pc = h * 256 + tid;
    const int pl = pc >> 6, c = pc & 63;
    float m = -FLT_MAX;
#pragma unroll
    for (int k = 0; k < NK; k++) m = fmaxf(m, Z[(pl * NK + k) * 68 + c]);
    x1[(size_t)(p0 + pl) * 64 + c] = m + b1b[c];
  }
}

// v[j,c] = x1_j . W2[64+d][c]
__global__ __launch_bounds__(256) void kv(const float* __restrict__ x1,
                                          const float* __restrict__ W2,
                                          float* __restrict__ v) {
  const int c = threadIdx.x & 127;
  const int sub = threadIdx.x >> 7;
  float wv[64];
#pragma unroll
  for (int d = 0; d < 64; d++) wv[d] = W2[(64 + d) * 128 + c];
  const int pbase = blockIdx.x * 64 + sub * 32;
  for (int i = 0; i < 32; i++) {
    const int p = pbase + i;
    const float4* xr = (const float4*)(x1 + (size_t)p * 64);
    float a0 = 0.f, a1 = 0.f;
#pragma unroll
    for (int dq = 0; dq < 16; dq++) {
      float4 xv = xr[dq];
      a0 = fmaf(xv.x, wv[dq * 4 + 0], a0);
      a1 = fmaf(xv.y, wv[dq * 4 + 1], a1);
      a0 = fmaf(xv.z, wv[dq * 4 + 2], a0);
      a1 = fmaf(xv.w, wv[dq * 4 + 3], a1);
    }
    v[(size_t)p * 128 + c] = a0 + a1;
  }
}

// Bc (192x128) and const bias cb (128)
__global__ __launch_bounds__(256) void kprep(const float* __restrict__ W2,
                                             const float* __restrict__ Wl,
                                             const float* __restrict__ b2,
                                             const float* __restrict__ bl,
                                             float* __restrict__ Bc,
                                             float* __restrict__ cb) {
  const int t = blockIdx.x * 256 + threadIdx.x;  // 8192
  const int d = t >> 7, c = t & 127;
  float s = Wl[d * 128 + c];
  for (int e = 0; e < 128; e++)
    s = fmaf(W2[d * 128 + e] - W2[(64 + d) * 128 + e], Wl[(64 + e) * 128 + c], s);
  Bc[d * 128 + c] = s;
  Bc[(64 + 2 * d) * 128 + c] = Wl[(64 + 2 * d) * 128 + c];
  Bc[(64 + 2 * d + 1) * 128 + c] = Wl[(64 + 2 * d + 1) * 128 + c];
  if (d == 0) {
    float sb = bl[c];
    for (int e = 0; e < 128; e++) sb = fmaf(b2[e], Wl[(64 + e) * 128 + c], sb);
    cb[c] = sb;
  }
}

// Final fused: AT = [x1^T ; maxgather(v)^T], GEMM with Bc, per-tile max.
#define ATS 72
#define BSS 132
__global__ __launch_bounds__(256) void kgemm(const float* __restrict__ x1,
                                             const float* __restrict__ v,
                                             const int* __restrict__ idx,
                                             const float* __restrict__ Bc,
                                             float* __restrict__ partial) {
  __shared__ float AT[192 * ATS];
  __shared__ float BS[16 * BSS];
  int* idxs = (int*)BS;
  const int tid = threadIdx.x;
  const int cloud = blockIdx.x >> 4;
  const int mb = blockIdx.x & 15;
  const int pbase = cloud * 1024 + mb * 64;

#pragma unroll
  for (int r = 0; r < 5; r++) {
    int id = r * 256 + tid;
    idxs[id] = idx[(size_t)pbase * NK + id];
  }
#pragma unroll
  for (int r = 0; r < 16; r++) {
    int id = r * 256 + tid;
    int m = id >> 6, k = id & 63;
    AT[k * ATS + m] = x1[(size_t)(pbase + m) * 64 + k];
  }
  __syncthreads();
#pragma unroll
  for (int r = 0; r < 32; r++) {
    int id = r * 256 + tid;
    int m = id >> 7, kk = id & 127;
    const int* ip = &idxs[m * NK];
    float mx = -FLT_MAX;
#pragma unroll
    for (int k = 0; k < NK; k++) mx = fmaxf(mx, v[(size_t)ip[k] * 128 + kk]);
    AT[(64 + kk) * ATS + m] = mx;
  }
  __syncthreads();

  const int tr = tid >> 4, tc = tid & 15;
  float acc[4][8];
#pragma unroll
  for (int i = 0; i < 4; i++)
#pragma unroll
    for (int n = 0; n < 8; n++) acc[i][n] = 0.f;
  for (int kc = 0; kc < 12; kc++) {
#pragma unroll
    for (int r = 0; r < 8; r++) {
      int id = r * 256 + tid;
      int row = id >> 7, col = id & 127;
      BS[row * BSS + col] = Bc[(size_t)(kc * 16 + row) * 128 + col];
    }
    __syncthreads();
#pragma unroll
    for (int k = 0; k < 16; k++) {
      int kg = kc * 16 + k;
      float4 a = *(const float4*)&AT[kg * ATS + tr * 4];
      float4 b0 = *(const float4*)&BS[k * BSS + tc * 8];
      float4 b1 = *(const float4*)&BS[k * BSS + tc * 8 + 4];
      float av[4] = {a.x, a.y, a.z, a.w};
      float bv[8] = {b0.x, b0.y, b0.z, b0.w, b1.x, b1.y, b1.z, b1.w};
#pragma unroll
      for (int i = 0; i < 4; i++)
#pragma unroll
        for (int n = 0; n < 8; n++) acc[i][n] = fmaf(av[i], bv[n], acc[i][n]);
    }
    __syncthreads();
  }
#pragma unroll
  for (int n = 0; n < 8; n++) {
    float m4 = fmaxf(fmaxf(acc[0][n], acc[1][n]), fmaxf(acc[2][n], acc[3][n]));
    BS[tr * BSS + tc * 8 + n] = m4;
  }
  __syncthreads();
  if (tid < 128) {
    float m = -FLT_MAX;
#pragma unroll
    for (int rr = 0; rr < 16; rr++) m = fmaxf(m, BS[rr * BSS + tid]);
    partial[(size_t)blockIdx.x * 128 + tid] = m;
  }
}

__global__ __launch_bounds__(256) void kred(const float* __restrict__ partial,
                                            const float* __restrict__ cb,
                                            float* __restrict__ out) {
  int t = blockIdx.x * 256 + threadIdx.x;  // 4096
  int b = t >> 7, c = t & 127;
  float m = -FLT_MAX;
#pragma unroll
  for (int mb = 0; mb < 16; mb++) m = fmaxf(m, partial[(size_t)(b * 16 + mb) * 128 + c]);
  out[t] = m + cb[c];
}

// ---------------------------------------------------------------------------
extern "C" void kernel_launch(void* const* d_in, const int* in_sizes, int n_in,
                              void* d_out, int out_size, void* d_ws, size_t ws_size,
                              hipStream_t stream) {
  const float* pos = (const float*)d_in[0];
  const float* W1a = (const float*)d_in[1];
  const float* b1a = (const float*)d_in[2];
  const float* g1 = (const float*)d_in[3];
  const float* be1 = (const float*)d_in[4];
  const float* W1b = (const float*)d_in[5];
  const float* b1b = (const float*)d_in[6];
  const float* W2 = (const float*)d_in[7];
  const float* b2 = (const float*)d_in[8];
  const float* Wl = (const float*)d_in[9];
  const float* bl = (const float*)d_in[10];
  float* out = (float*)d_out;

  // Base workspace (floats). D-matrix chunk after it.
  float* ws = (float*)d_ws;
  float* x1 = ws;                           // 2,097,152
  float* v = ws + 2097152;                  // 4,194,304
  int* idx = (int*)(ws + 6291456);          // 655,360
  float* d2b = ws + 6946816;                // 32,768
  double* Spart = (double*)(ws + 6979584);  // 128*42 doubles = 10,752 slots
  float* Bc = ws + 6990336;                 // 24,576
  float* cb = ws + 7014912;                 // 128
  float* ss = ws + 7015040;                 // 128
  float* partial = ws + 7015168;            // 65,536 -> end 7,080,704
  const size_t base = 7080704;
  float* D = ws + base;

  if (ws_size < base * sizeof(float)) return;  // fail soft

  // D chunk: 8 clouds (32 MB) for L2/L3 residency between kdist and kselect
  size_t avail = ws_size / sizeof(float) - base;
  int nc = 0;
  for (int c = 8; c >= 1; c >>= 1)
    if ((size_t)c * 1024 * 1024 <= avail) {
      nc = c;
      break;
    }

  // --- layer 1: kNN on pos (3D) ---
  kd2<<<128, 256, 0, stream>>>(pos, 3, d2b);
  if (nc > 0) {
    for (int c0 = 0; c0 < NB; c0 += nc) {
      kdist<3><<<nc * 64, 256, 0, stream>>>(pos, d2b, c0, D);
      kselect<<<nc * 256, 256, 0, stream>>>(D, c0, idx);
    }
  } else {
    kknn<3><<<512, 256, 0, stream>>>(pos, d2b, idx);
  }

  // --- EdgeConv1 (analytic BN via exact 6-dim moments, atomic-free) ---
  kstats<<<128, 256, 0, stream>>>(pos, idx, Spart);
  kbn<<<1, 64, 0, stream>>>(Spart, W1a, b1a, g1, be1, ss);
  kec1<<<4096, 256, 0, stream>>>(pos, idx, ss, W1a, b1a, W1b, b1b, x1);

  // --- layer 2: kNN on x1 (64D) ---
  kd2<<<128, 256, 0, stream>>>(x1, 64, d2b);
  if (nc > 0) {
    for (int c0 = 0; c0 < NB; c0 += nc) {
      kdist<64><<<nc * 64, 256, 0, stream>>>(x1, d2b, c0, D);
      kselect<<<nc * 256, 256, 0, stream>>>(D, c0, idx);
    }
  } else {
    kknn<64><<<512, 256, 0, stream>>>(x1, d2b, idx);
  }

  // --- EdgeConv2 factored + fused final linear + pool ---
  kv<<<512, 256, 0, stream>>>(x1, W2, v);
  kprep<<<32, 256, 0, stream>>>(W2, Wl, b2, bl, Bc, cb);
  kgemm<<<512, 256, 0, stream>>>(x1, v, idx, Bc, partial);
  kred<<<16, 256, 0, stream>>>(partial, cb, out);
}

// Round 6
// 454.346 us; speedup vs baseline: 3.1301x; 1.2315x over previous
//
#include <hip/hip_runtime.h>
#include <cfloat>
#include <cstdint>

#define NB 32
#define NP 1024
#define NK 20
#define NPTS 32768  // NB*NP

// ---------------------------------------------------------------------------
// d2[p] = sum x^2, SINGLE sequential FMA chain (order-matched with kdist's
// per-acc chain so diagonal dist = fmaf(-2,d2p,2*d2p) = exact 0).
// ---------------------------------------------------------------------------
__global__ __launch_bounds__(256) void kd2(const float* __restrict__ x, int dim,
                                           float* __restrict__ d2) {
  int p = blockIdx.x * 256 + threadIdx.x;
  if (p >= NPTS) return;
  if (dim == 64) {
    const float4* xr = (const float4*)(x + (size_t)p * 64);
    float s = 0.f;
#pragma unroll
    for (int dq = 0; dq < 16; dq++) {
      float4 v = xr[dq];
      s = fmaf(v.x, v.x, s);
      s = fmaf(v.y, v.y, s);
      s = fmaf(v.z, v.z, s);
      s = fmaf(v.w, v.w, s);
    }
    d2[p] = s;
  } else {
    float s = 0.f;
#pragma unroll
    for (int d = 0; d < 3; d++) {
      float v = x[p * 3 + d];
      s = fmaf(v, v, s);
    }
    d2[p] = s;
  }
}

// ---------------------------------------------------------------------------
// kdist: full per-cloud distance matrix, 128x128 tile per block.
// ---------------------------------------------------------------------------
template <int DIM>
__global__ __launch_bounds__(256) void kdist(const float* __restrict__ x,
                                             const float* __restrict__ d2,
                                             int c0, float* __restrict__ D) {
  constexpr int KC = (DIM == 64) ? 32 : 3;
  __shared__ float As[KC][132];
  __shared__ float Bs[KC][132];
  const int tid = threadIdx.x;
  const int cloud = blockIdx.x >> 6;  // within chunk
  const int t = blockIdx.x & 63;
  const int tr0 = (t >> 3) * 128, tc0 = (t & 7) * 128;
  const int cb = (c0 + cloud) * 1024;
  const int tr = tid >> 4, tc = tid & 15;

  float acc[8][8];
#pragma unroll
  for (int i = 0; i < 8; i++)
#pragma unroll
    for (int j = 0; j < 8; j++) acc[i][j] = 0.f;

  for (int kc = 0; kc < DIM; kc += KC) {
    __syncthreads();
    if constexpr (DIM == 64) {
      const int row = tid >> 1, seg = tid & 1;
      const float4* sa = (const float4*)(x + (size_t)(cb + tr0 + row) * 64 + kc + seg * 16);
      const float4* sb = (const float4*)(x + (size_t)(cb + tc0 + row) * 64 + kc + seg * 16);
#pragma unroll
      for (int i = 0; i < 4; i++) {
        float4 va = sa[i];
        float4 vb = sb[i];
        const int k0 = seg * 16 + i * 4;
        As[k0 + 0][row] = va.x;
        As[k0 + 1][row] = va.y;
        As[k0 + 2][row] = va.z;
        As[k0 + 3][row] = va.w;
        Bs[k0 + 0][row] = vb.x;
        Bs[k0 + 1][row] = vb.y;
        Bs[k0 + 2][row] = vb.z;
        Bs[k0 + 3][row] = vb.w;
      }
    } else {
      if (tid < 128) {
#pragma unroll
        for (int d = 0; d < 3; d++) {
          As[d][tid] = x[(size_t)(cb + tr0 + tid) * 3 + d];
          Bs[d][tid] = x[(size_t)(cb + tc0 + tid) * 3 + d];
        }
      }
    }
    __syncthreads();
#pragma unroll
    for (int k = 0; k < KC; k++) {
      float a[8], b[8];
      *(float4*)&a[0] = *(const float4*)&As[k][tr * 8];
      *(float4*)&a[4] = *(const float4*)&As[k][tr * 8 + 4];
      *(float4*)&b[0] = *(const float4*)&Bs[k][tc * 8];
      *(float4*)&b[4] = *(const float4*)&Bs[k][tc * 8 + 4];
#pragma unroll
      for (int i = 0; i < 8; i++)
#pragma unroll
        for (int j = 0; j < 8; j++) acc[i][j] = fmaf(a[i], b[j], acc[i][j]);
    }
  }
  float d2r[8], d2c[8];
#pragma unroll
  for (int i = 0; i < 8; i++) d2r[i] = d2[cb + tr0 + tr * 8 + i];
#pragma unroll
  for (int j = 0; j < 8; j++) d2c[j] = d2[cb + tc0 + tc * 8 + j];
#pragma unroll
  for (int i = 0; i < 8; i++) {
    float o[8];
#pragma unroll
    for (int j = 0; j < 8; j++) o[j] = fmaf(-2.f, acc[i][j], d2r[i] + d2c[j]);
    float* dst = &D[(size_t)(cloud * 1024 + tr0 + tr * 8 + i) * 1024 + tc0 + tc * 8];
    *(float4*)&dst[0] = *(const float4*)&o[0];
    *(float4*)&dst[4] = *(const float4*)&o[4];
  }
}

// ---------------------------------------------------------------------------
// kselect: exact top-20 via pivot selection (keys distinct by construction).
// ---------------------------------------------------------------------------
__global__ __launch_bounds__(256) void kselect(const float* __restrict__ D,
                                               int c0, int* __restrict__ idxo) {
  __shared__ unsigned long long lw[4][64];
  const int lane = threadIdx.x & 63;
  const int sub = threadIdx.x >> 6;
  const int pchunk = blockIdx.x * 4 + sub;  // point within chunk
  const int pg = c0 * 1024 + pchunk;        // global point
  const int gbase = (pg >> 10) << 10;       // cloud base (global)

  unsigned long long key[16];
  const float4* dr = (const float4*)(D + (size_t)pchunk * 1024 + lane * 4);
#pragma unroll
  for (int i = 0; i < 4; i++) {
    float4 d4 = dr[i * 64];  // q = i*256 + lane*4 ..+3
    float dv[4] = {d4.x, d4.y, d4.z, d4.w};
#pragma unroll
    for (int j = 0; j < 4; j++) {
      unsigned int u = __float_as_uint(dv[j]);
      u ^= (((int)u >> 31) | 0x80000000u);  // sortable transform
      key[i * 4 + j] = ((unsigned long long)u << 10) | (unsigned)(i * 256 + lane * 4 + j);
    }
  }

  unsigned long long mn = key[0], mx = key[0];
#pragma unroll
  for (int i = 1; i < 16; i++) {
    mn = key[i] < mn ? key[i] : mn;
    mx = key[i] > mx ? key[i] : mx;
  }
#pragma unroll
  for (int s = 1; s < 64; s <<= 1) {
    unsigned long long a = __shfl_xor(mn, s, 64);
    unsigned long long b = __shfl_xor(mx, s, 64);
    mn = a < mn ? a : mn;
    mx = b > mx ? b : mx;
  }
  unsigned long long lo = mn, hi = mx + 1, mid = hi;
  bool found = false;
  for (int it = 0; it < 48 && !found; ++it) {
    unsigned long long m2 = lo + ((hi - lo) >> 1);
    int cnt = 0;
#pragma unroll
    for (int i = 0; i < 16; i++) cnt += (key[i] < m2) ? 1 : 0;
#pragma unroll
    for (int s = 1; s < 64; s <<= 1) cnt += __shfl_xor(cnt, s, 64);
    if (cnt < 20)
      lo = m2;
    else if (cnt > 63)
      hi = m2;
    else {
      mid = m2;
      found = true;
    }
  }

  unsigned int mask = 0;
#pragma unroll
  for (int i = 0; i < 16; i++) mask |= (key[i] < mid) ? (1u << i) : 0u;
  const int lc = __popc(mask);
  int x = lc;
#pragma unroll
  for (int s = 1; s < 64; s <<= 1) {
    int y = __shfl_up(x, s, 64);
    if (lane >= s) x += y;
  }
  int off = x - lc;                    // exclusive prefix
  const int ctot = __shfl(x, 63, 64);  // total candidates
  const int c = ctot < 64 ? ctot : 64;
  unsigned long long* w = lw[sub];
#pragma unroll
  for (int i = 0; i < 16; i++) {
    if ((mask & (1u << i)) && off < 64) {
      w[off] = key[i];
      off++;
    }
  }
  __builtin_amdgcn_wave_barrier();

  const unsigned long long K = w[lane < c ? lane : 0];
  int rank = 0;
  for (int m = 0; m < c; m++) {
    const unsigned long long Km = w[m];  // broadcast read
    rank += (K > Km) ? 1 : 0;
  }
  if (lane < c && rank < NK)
    idxo[(size_t)pg * NK + rank] = gbase + (int)(K & 1023u);
}

// ---------------------------------------------------------------------------
// FALLBACK kNN (used only if ws_size can't fit a 1-cloud distance matrix).
// ---------------------------------------------------------------------------
template <int DIM>
__global__ __launch_bounds__(256) void kknn(const float* __restrict__ x,
                                            const float* __restrict__ d2,
                                            int* __restrict__ idxo) {
  constexpr int STR = (DIM == 64) ? 68 : 4;
  __shared__ float smem[10240];
  float* tile = smem;
  float* dt = smem + 64 * STR;
  float* mD = smem;
  int* mI = (int*)(smem + 5120);

  const int tid = threadIdx.x;
  const int pt = tid & 63;
  const int qt = tid >> 6;
  const int cloud = blockIdx.x >> 4;
  const int blk = blockIdx.x & 15;
  const int p = cloud * 1024 + blk * 64 + pt;
  const int cbase = cloud * 1024;

  float xp[DIM];
#pragma unroll
  for (int d = 0; d < DIM; d++) xp[d] = x[(size_t)p * DIM + d];
  const float d2p = d2[p];

  float bd[NK];
  int bi[NK];
#pragma unroll
  for (int s = 0; s < NK; s++) {
    bd[s] = FLT_MAX;
    bi[s] = 0x7fffffff;
  }
  float wd = FLT_MAX;
  int wi = 0x7fffffff;
  int wsl = 0;

  for (int t = 0; t < 16; t++) {
    __syncthreads();
    if (tid < 64) {
#pragma unroll
      for (int d = 0; d < DIM; d++) tile[tid * STR + d] = x[(size_t)(cbase + t * 64 + tid) * DIM + d];
      dt[tid] = d2[cbase + t * 64 + tid];
    }
    __syncthreads();
    for (int jj = 0; jj < 16; jj++) {
      const int j = jj * 4 + qt;
      float s = 0.f;
#pragma unroll
      for (int d = 0; d < DIM; d++) s = fmaf(xp[d], tile[j * STR + d], s);
      const float dist = fmaf(-2.f, s, d2p + dt[j]);
      const int qg = cbase + t * 64 + j;
      const bool ins = (dist < wd) || (dist == wd && qg < wi);
      if (ins) {
#pragma unroll
        for (int sl = 0; sl < NK; sl++)
          if (sl == wsl) {
            bd[sl] = dist;
            bi[sl] = qg;
          }
        wd = bd[0];
        wi = bi[0];
        wsl = 0;
#pragma unroll
        for (int sl = 1; sl < NK; sl++) {
          const bool worse = (bd[sl] > wd) || (bd[sl] == wd && bi[sl] > wi);
          if (worse) {
            wd = bd[sl];
            wi = bi[sl];
            wsl = sl;
          }
        }
      }
    }
  }
  __syncthreads();
#pragma unroll
  for (int s = 0; s < NK; s++) {
    mD[pt * 80 + qt * 20 + s] = bd[s];
    mI[pt * 80 + qt * 20 + s] = bi[s];
  }
  __syncthreads();
  if (tid < 128) {
    const int pt2 = tid >> 1, h = tid & 1;
    const int base = pt2 * 80 + h * 40;
    float cd[40];
    int ci[40];
#pragma unroll
    for (int a = 0; a < 40; a++) {
      cd[a] = mD[base + a];
      ci[a] = mI[base + a];
    }
    int rank[40];
#pragma unroll
    for (int a = 0; a < 40; a++) rank[a] = 0;
#pragma unroll
    for (int a = 0; a < 40; a++)
#pragma unroll
      for (int b = a + 1; b < 40; b++) {
        const bool abet = (cd[a] < cd[b]) || (cd[a] == cd[b] && ci[a] < ci[b]);
        if (abet)
          rank[b]++;
        else
          rank[a]++;
      }
#pragma unroll
    for (int a = 0; a < 40; a++)
      if (rank[a] < NK) {
        mD[base + rank[a]] = cd[a];
        mI[base + rank[a]] = ci[a];
      }
  }
  __syncthreads();
  if (tid < 64) {
    const int base = tid * 80;
    float cd[40];
    int ci[40];
#pragma unroll
    for (int a = 0; a < 20; a++) {
      cd[a] = mD[base + a];
      ci[a] = mI[base + a];
      cd[20 + a] = mD[base + 40 + a];
      ci[20 + a] = mI[base + 40 + a];
    }
    int rank[40];
#pragma unroll
    for (int a = 0; a < 40; a++) rank[a] = 0;
#pragma unroll
    for (int a = 0; a < 40; a++)
#pragma unroll
      for (int b = a + 1; b < 40; b++) {
        const bool abet = (cd[a] < cd[b]) || (cd[a] == cd[b] && ci[a] < ci[b]);
        if (abet)
          rank[b]++;
        else
          rank[a]++;
      }
    const int po = cloud * 1024 + blk * 64 + tid;
#pragma unroll
    for (int a = 0; a < 40; a++)
      if (rank[a] < NK) idxo[(size_t)po * NK + rank[a]] = ci[a];
  }
}

// ---------------------------------------------------------------------------
// Edge moments, atomic-free: wave butterfly -> LDS cross-wave -> per-block
// partial (double). kbn reduces the 128 partials.
// ---------------------------------------------------------------------------
__global__ __launch_bounds__(256) void kstats(const float* __restrict__ pos,
                                              const int* __restrict__ idx,
                                              double* __restrict__ Spart) {
  __shared__ float red[4][42];
  const int tid = threadIdx.x;
  const int w = tid >> 6;
  int p = blockIdx.x * 256 + tid;
  float xi0 = pos[p * 3], xi1 = pos[p * 3 + 1], xi2 = pos[p * 3 + 2];
  float s1[6];
  float s2[36];
#pragma unroll
  for (int a = 0; a < 6; a++) s1[a] = 0.f;
#pragma unroll
  for (int a = 0; a < 36; a++) s2[a] = 0.f;
  for (int k = 0; k < NK; k++) {
    int j = idx[p * NK + k];
    float e[6];
    e[0] = xi0;
    e[1] = xi1;
    e[2] = xi2;
    e[3] = pos[j * 3] - xi0;
    e[4] = pos[j * 3 + 1] - xi1;
    e[5] = pos[j * 3 + 2] - xi2;
#pragma unroll
    for (int a = 0; a < 6; a++) {
      s1[a] += e[a];
#pragma unroll
      for (int b = 0; b < 6; b++) s2[a * 6 + b] = fmaf(e[a], e[b], s2[a * 6 + b]);
    }
  }
#pragma unroll
  for (int a = 0; a < 6; a++) {
#pragma unroll
    for (int m = 1; m < 64; m <<= 1) s1[a] += __shfl_xor(s1[a], m, 64);
  }
#pragma unroll
  for (int a = 0; a < 36; a++) {
#pragma unroll
    for (int m = 1; m < 64; m <<= 1) s2[a] += __shfl_xor(s2[a], m, 64);
  }
  if ((tid & 63) == 0) {
#pragma unroll
    for (int a = 0; a < 6; a++) red[w][a] = s1[a];
#pragma unroll
    for (int a = 0; a < 36; a++) red[w][6 + a] = s2[a];
  }
  __syncthreads();
  if (tid < 42) {
    double t = (double)red[0][tid] + (double)red[1][tid] + (double)red[2][tid] +
               (double)red[3][tid];
    Spart[(size_t)blockIdx.x * 42 + tid] = t;
  }
}

// BN scale/shift from moments (reduce 128 partials, then exact in double)
__global__ void kbn(const double* __restrict__ Spart, const float* __restrict__ W1a,
                    const float* __restrict__ b1a, const float* __restrict__ g1,
                    const float* __restrict__ be1, float* __restrict__ ss) {
  __shared__ double S[42];
  int c = threadIdx.x;  // 64
  if (c < 42) {
    double t = 0.0;
    for (int b = 0; b < 128; b++) t += Spart[(size_t)b * 42 + c];
    S[c] = t;
  }
  __syncthreads();
  double w[6];
#pragma unroll
  for (int d = 0; d < 6; d++) w[d] = (double)W1a[d * 64 + c];
  double b = (double)b1a[c];
  const double invN = 1.0 / (double)((size_t)NPTS * NK);
  double m1 = 0.0;
#pragma unroll
  for (int d = 0; d < 6; d++) m1 += w[d] * S[d];
  m1 *= invN;
  double q = 0.0;
#pragma unroll
  for (int a = 0; a < 6; a++)
#pragma unroll
    for (int d = 0; d < 6; d++) q += w[a] * w[d] * S[6 + a * 6 + d];
  q *= invN;
  double mu = m1 + b;
  double eh2 = q + 2.0 * b * m1 + b * b;
  double var = eh2 - mu * mu;
  if (var < 0.0) var = 0.0;
  double inv = 1.0 / sqrt(var + 1e-5);
  double sc = (double)g1[c] * inv;
  ss[c] = (float)sc;
  ss[64 + c] = (float)((double)be1[c] - mu * sc);
}

// ---------------------------------------------------------------------------
// EdgeConv1 fused, GEMM-structured. Block = 6 points = 120 edges.
// LDS 52 KB -> 3 blocks/CU (was 8 pts / 62 KB / 2 blocks).
// Phase 0: parallel gather of 120 neighbor coords -> nbr (kills the serial
//          scalar-load chain of the old phase 1).
// Phase 1: Z[120][64] = relu(BN(edge)) (wave-per-point, lane = channel).
// Phase 2: Y = Z @ W1b, 4x8 register tile (row guard r<120 is wave-uniform).
// Phase 3: x1[p][c] = max_k Y[p*20+k][c] + b1b[c].
// ---------------------------------------------------------------------------
#define EC1P 6
__global__ __launch_bounds__(256) void kec1(const float* __restrict__ pos,
                                            const int* __restrict__ idx,
                                            const float* __restrict__ ss,
                                            const float* __restrict__ W1a,
                                            const float* __restrict__ b1a,
                                            const float* __restrict__ W1b,
                                            const float* __restrict__ b1b,
                                            float* __restrict__ x1) {
  __shared__ float Z[120 * 68];   // 32640 B (Y overwrites)
  __shared__ float BW[64 * 68];   // 17408 B
  __shared__ float nbr[120 * 4];  // 1920 B
  const int tid = threadIdx.x;
  const int lane = tid & 63;
  const int w = tid >> 6;
  const int p0 = blockIdx.x * EC1P;
  const int npts = (NPTS - p0 < EC1P) ? (NPTS - p0) : EC1P;

  // stage W1b (64x64) -> BW (stride 68)
#pragma unroll
  for (int r = 0; r < 4; r++) {
    const int id = r * 256 + tid;  // 1024 float4
    const int d = id >> 4, c4 = (id & 15) * 4;
    const float4 w4 = *(const float4*)&W1b[d * 64 + c4];
    *(float4*)&BW[d * 68 + c4] = w4;
  }
  // phase 0: parallel neighbor-coordinate gather
  if (tid < 120) {
    const int pl = tid / 20;
    if (pl < npts) {
      const int j = idx[(size_t)p0 * NK + tid];
      nbr[tid * 4 + 0] = pos[j * 3 + 0];
      nbr[tid * 4 + 1] = pos[j * 3 + 1];
      nbr[tid * 4 + 2] = pos[j * 3 + 2];
    }
  }

  float wdf[3], wbt[3];
#pragma unroll
  for (int d = 0; d < 3; d++) {
    const float top = W1a[d * 64 + lane];
    const float bot = W1a[(3 + d) * 64 + lane];
    wdf[d] = top - bot;
    wbt[d] = bot;
  }
  const float b1 = b1a[lane];
  const float sc = ss[lane];
  const float sh = ss[64 + lane];
  __syncthreads();

  // phase 1: Z rows (wave w -> points w, w+4)
#pragma unroll
  for (int pp = 0; pp < 2; pp++) {
    const int pl = w + 4 * pp;
    if (pl < npts) {
      const int p = p0 + pl;
      const float xi0 = pos[p * 3], xi1 = pos[p * 3 + 1], xi2 = pos[p * 3 + 2];
      const float pu = fmaf(xi2, wdf[2], fmaf(xi1, wdf[1], fmaf(xi0, wdf[0], b1)));
      for (int k = 0; k < NK; k++) {
        const float4 nb = *(const float4*)&nbr[(pl * NK + k) * 4];  // broadcast
        const float pv = fmaf(nb.z, wbt[2], fmaf(nb.y, wbt[1], nb.x * wbt[0]));
        Z[(pl * NK + k) * 68 + lane] = fmaxf(fmaf(pu + pv, sc, sh), 0.f);
      }
    }
  }
  __syncthreads();

  // phase 2: Y(120x64) = Z(120x64) @ BW(64x64); thread tile 4 rows x 8 ch
  const int tc = tid & 7;
  const int tm = tid >> 3;  // 0..31; rows tm + 32*i
  float acc[4][8];
#pragma unroll
  for (int i = 0; i < 4; i++)
#pragma unroll
    for (int n = 0; n < 8; n++) acc[i][n] = 0.f;

#pragma unroll
  for (int d4 = 0; d4 < 16; d4++) {
    float b[4][8];
#pragma unroll
    for (int r = 0; r < 4; r++) {
      *(float4*)&b[r][0] = *(const float4*)&BW[(d4 * 4 + r) * 68 + tc * 8];
      *(float4*)&b[r][4] = *(const float4*)&BW[(d4 * 4 + r) * 68 + tc * 8 + 4];
    }
#pragma unroll
    for (int i = 0; i < 4; i++) {
      const int row = tm + 32 * i;
      if (row < 120) {  // wave-uniform guard
        float a[4];
        *(float4*)&a[0] = *(const float4*)&Z[row * 68 + d4 * 4];
#pragma unroll
        for (int r = 0; r < 4; r++)
#pragma unroll
          for (int n = 0; n < 8; n++) acc[i][n] = fmaf(a[r], b[r][n], acc[i][n]);
      }
    }
  }
  __syncthreads();

#pragma unroll
  for (int i = 0; i < 4; i++) {
    const int row = tm + 32 * i;
    if (row < 120) {
      *(float4*)&Z[row * 68 + tc * 8] = *(const float4*)&acc[i][0];
      *(float4*)&Z[row * 68 + tc * 8 + 4] = *(const float4*)&acc[i][4];
    }
  }
  __syncthreads();

  // phase 3: per (point, channel) max over 20 edge rows, + b1b
#pragma unroll
  for (int h = 0; h < 2; h++) {
    const int pc = h * 256 + tid;  // 0..511 ; need npts*64 <= 384
    const int pl = pc >> 6, c = pc & 63;
    if (pl < npts) {
      float m = -FLT_MAX;
#pragma unroll
      for (int k = 0; k < NK; k++) m = fmaxf(m, Z[(pl * NK + k) * 68 + c]);
      x1[(size_t)(p0 + pl) * 64 + c] = m + b1b[c];
    }
  }
}

// v[j,c] = x1_j . W2[64+d][c]
__global__ __launch_bounds__(256) void kv(const float* __restrict__ x1,
                                          const float* __restrict__ W2,
                                          float* __restrict__ v) {
  const int c = threadIdx.x & 127;
  const int sub = threadIdx.x >> 7;
  float wv[64];
#pragma unroll
  for (int d = 0; d < 64; d++) wv[d] = W2[(64 + d) * 128 + c];
  const int pbase = blockIdx.x * 64 + sub * 32;
  for (int i = 0; i < 32; i++) {
    const int p = pbase + i;
    const float4* xr = (const float4*)(x1 + (size_t)p * 64);
    float a0 = 0.f, a1 = 0.f;
#pragma unroll
    for (int dq = 0; dq < 16; dq++) {
      float4 xv = xr[dq];
      a0 = fmaf(xv.x, wv[dq * 4 + 0], a0);
      a1 = fmaf(xv.y, wv[dq * 4 + 1], a1);
      a0 = fmaf(xv.z, wv[dq * 4 + 2], a0);
      a1 = fmaf(xv.w, wv[dq * 4 + 3], a1);
    }
    v[(size_t)p * 128 + c] = a0 + a1;
  }
}

// Bc (192x128) and const bias cb (128)
__global__ __launch_bounds__(256) void kprep(const float* __restrict__ W2,
                                             const float* __restrict__ Wl,
                                             const float* __restrict__ b2,
                                             const float* __restrict__ bl,
                                             float* __restrict__ Bc,
                                             float* __restrict__ cb) {
  const int t = blockIdx.x * 256 + threadIdx.x;  // 8192
  const int d = t >> 7, c = t & 127;
  float s = Wl[d * 128 + c];
  for (int e = 0; e < 128; e++)
    s = fmaf(W2[d * 128 + e] - W2[(64 + d) * 128 + e], Wl[(64 + e) * 128 + c], s);
  Bc[d * 128 + c] = s;
  Bc[(64 + 2 * d) * 128 + c] = Wl[(64 + 2 * d) * 128 + c];
  Bc[(64 + 2 * d + 1) * 128 + c] = Wl[(64 + 2 * d + 1) * 128 + c];
  if (d == 0) {
    float sb = bl[c];
    for (int e = 0; e < 128; e++) sb = fmaf(b2[e], Wl[(64 + e) * 128 + c], sb);
    cb[c] = sb;
  }
}

// Final fused: AT = [x1^T ; maxgather(v)^T], GEMM with Bc, per-tile max.
#define ATS 72
#define BSS 132
__global__ __launch_bounds__(256) void kgemm(const float* __restrict__ x1,
                                             const float* __restrict__ v,
                                             const int* __restrict__ idx,
                                             const float* __restrict__ Bc,
                                             float* __restrict__ partial) {
  __shared__ float AT[192 * ATS];
  __shared__ float BS[16 * BSS];
  int* idxs = (int*)BS;
  const int tid = threadIdx.x;
  const int cloud = blockIdx.x >> 4;
  const int mb = blockIdx.x & 15;
  const int pbase = cloud * 1024 + mb * 64;

#pragma unroll
  for (int r = 0; r < 5; r++) {
    int id = r * 256 + tid;
    idxs[id] = idx[(size_t)pbase * NK + id];
  }
#pragma unroll
  for (int r = 0; r < 16; r++) {
    int id = r * 256 + tid;
    int m = id >> 6, k = id & 63;
    AT[k * ATS + m] = x1[(size_t)(pbase + m) * 64 + k];
  }
  __syncthreads();
#pragma unroll
  for (int r = 0; r < 32; r++) {
    int id = r * 256 + tid;
    int m = id >> 7, kk = id & 127;
    const int* ip = &idxs[m * NK];
    float mx = -FLT_MAX;
#pragma unroll
    for (int k = 0; k < NK; k++) mx = fmaxf(mx, v[(size_t)ip[k] * 128 + kk]);
    AT[(64 + kk) * ATS + m] = mx;
  }
  __syncthreads();

  const int tr = tid >> 4, tc = tid & 15;
  float acc[4][8];
#pragma unroll
  for (int i = 0; i < 4; i++)
#pragma unroll
    for (int n = 0; n < 8; n++) acc[i][n] = 0.f;
  for (int kc = 0; kc < 12; kc++) {
#pragma unroll
    for (int r = 0; r < 8; r++) {
      int id = r * 256 + tid;
      int row = id >> 7, col = id & 127;
      BS[row * BSS + col] = Bc[(size_t)(kc * 16 + row) * 128 + col];
    }
    __syncthreads();
#pragma unroll
    for (int k = 0; k < 16; k++) {
      int kg = kc * 16 + k;
      float4 a = *(const float4*)&AT[kg * ATS + tr * 4];
      float4 b0 = *(const float4*)&BS[k * BSS + tc * 8];
      float4 b1 = *(const float4*)&BS[k * BSS + tc * 8 + 4];
      float av[4] = {a.x, a.y, a.z, a.w};
      float bv[8] = {b0.x, b0.y, b0.z, b0.w, b1.x, b1.y, b1.z, b1.w};
#pragma unroll
      for (int i = 0; i < 4; i++)
#pragma unroll
        for (int n = 0; n < 8; n++) acc[i][n] = fmaf(av[i], bv[n], acc[i][n]);
    }
    __syncthreads();
  }
#pragma unroll
  for (int n = 0; n < 8; n++) {
    float m4 = fmaxf(fmaxf(acc[0][n], acc[1][n]), fmaxf(acc[2][n], acc[3][n]));
    BS[tr * BSS + tc * 8 + n] = m4;
  }
  __syncthreads();
  if (tid < 128) {
    float m = -FLT_MAX;
#pragma unroll
    for (int rr = 0; rr < 16; rr++) m = fmaxf(m, BS[rr * BSS + tid]);
    partial[(size_t)blockIdx.x * 128 + tid] = m;
  }
}

__global__ __launch_bounds__(256) void kred(const float* __restrict__ partial,
                                            const float* __restrict__ cb,
                                            float* __restrict__ out) {
  int t = blockIdx.x * 256 + threadIdx.x;  // 4096
  int b = t >> 7, c = t & 127;
  float m = -FLT_MAX;
#pragma unroll
  for (int mb = 0; mb < 16; mb++) m = fmaxf(m, partial[(size_t)(b * 16 + mb) * 128 + c]);
  out[t] = m + cb[c];
}

// ---------------------------------------------------------------------------
extern "C" void kernel_launch(void* const* d_in, const int* in_sizes, int n_in,
                              void* d_out, int out_size, void* d_ws, size_t ws_size,
                              hipStream_t stream) {
  const float* pos = (const float*)d_in[0];
  const float* W1a = (const float*)d_in[1];
  const float* b1a = (const float*)d_in[2];
  const float* g1 = (const float*)d_in[3];
  const float* be1 = (const float*)d_in[4];
  const float* W1b = (const float*)d_in[5];
  const float* b1b = (const float*)d_in[6];
  const float* W2 = (const float*)d_in[7];
  const float* b2 = (const float*)d_in[8];
  const float* Wl = (const float*)d_in[9];
  const float* bl = (const float*)d_in[10];
  float* out = (float*)d_out;

  // Base workspace (floats). D-matrix chunk after it.
  float* ws = (float*)d_ws;
  float* x1 = ws;                           // 2,097,152
  float* v = ws + 2097152;                  // 4,194,304
  int* idx = (int*)(ws + 6291456);          // 655,360
  float* d2b = ws + 6946816;                // 32,768
  double* Spart = (double*)(ws + 6979584);  // 128*42 doubles = 10,752 slots
  float* Bc = ws + 6990336;                 // 24,576
  float* cb = ws + 7014912;                 // 128
  float* ss = ws + 7015040;                 // 128
  float* partial = ws + 7015168;            // 65,536 -> end 7,080,704
  const size_t base = 7080704;
  float* D = ws + base;

  if (ws_size < base * sizeof(float)) return;  // fail soft

  // D chunk: prefer the largest power-of-2 cloud count that fits (<= 32);
  // nc=32 -> single kdist+kselect pair per layer (fewest dispatches).
  size_t avail = ws_size / sizeof(float) - base;
  int nc = 0;
  for (int c = 32; c >= 1; c >>= 1)
    if ((size_t)c * 1024 * 1024 <= avail) {
      nc = c;
      break;
    }

  // --- layer 1: kNN on pos (3D) ---
  kd2<<<128, 256, 0, stream>>>(pos, 3, d2b);
  if (nc > 0) {
    for (int c0 = 0; c0 < NB; c0 += nc) {
      kdist<3><<<nc * 64, 256, 0, stream>>>(pos, d2b, c0, D);
      kselect<<<nc * 256, 256, 0, stream>>>(D, c0, idx);
    }
  } else {
    kknn<3><<<512, 256, 0, stream>>>(pos, d2b, idx);
  }

  // --- EdgeConv1 (analytic BN via exact 6-dim moments, atomic-free) ---
  kstats<<<128, 256, 0, stream>>>(pos, idx, Spart);
  kbn<<<1, 64, 0, stream>>>(Spart, W1a, b1a, g1, be1, ss);
  kec1<<<(NPTS + EC1P - 1) / EC1P, 256, 0, stream>>>(pos, idx, ss, W1a, b1a, W1b, b1b, x1);

  // --- layer 2: kNN on x1 (64D) ---
  kd2<<<128, 256, 0, stream>>>(x1, 64, d2b);
  if (nc > 0) {
    for (int c0 = 0; c0 < NB; c0 += nc) {
      kdist<64><<<nc * 64, 256, 0, stream>>>(x1, d2b, c0, D);
      kselect<<<nc * 256, 256, 0, stream>>>(D, c0, idx);
    }
  } else {
    kknn<64><<<512, 256, 0, stream>>>(x1, d2b, idx);
  }

  // --- EdgeConv2 factored + fused final linear + pool ---
  kv<<<512, 256, 0, stream>>>(x1, W2, v);
  kprep<<<32, 256, 0, stream>>>(W2, Wl, b2, bl, Bc, cb);
  kgemm<<<512, 256, 0, stream>>>(x1, v, idx, Bc, partial);
  kred<<<16, 256, 0, stream>>>(partial, cb, out);
}